// Round 1
// 2928.773 us; speedup vs baseline: 1.1764x; 1.1764x over previous
//
#include <hip/hip_runtime.h>
#include <hip/hip_bf16.h>
#include <math.h>

// ---------------------------------------------------------------------------
// MusicDiffusionTransformer forward, MI355X (gfx950).
// Round 6: replace latency-bound M=2 MLP kernels (mlp2k, ~233us each at
// 0.36% occupancy) with split-K two-phase streaming kernels (mlpA/mlpB).
// Everything else unchanged from round 5.
// ---------------------------------------------------------------------------

typedef unsigned short u16;
typedef __attribute__((ext_vector_type(8))) short short8;
typedef __attribute__((ext_vector_type(8))) unsigned short ushort8;
typedef __attribute__((ext_vector_type(4))) float f32x4;

#define MFMA_B16(a, b, c) __builtin_amdgcn_mfma_f32_16x16x32_bf16(a, b, c, 0, 0, 0)

__device__ __forceinline__ float gelu_f(float x) {
  return 0.5f * x * (1.f + erff(x * 0.70710678118654752f));
}
__device__ __forceinline__ u16 f2b(float x) {
  union { float f; unsigned u; } v;
  v.f = x;
  unsigned r = (v.u + 0x7FFF + ((v.u >> 16) & 1)) >> 16;
  return (u16)r;
}
__device__ __forceinline__ float b2f(u16 u) {
  union { unsigned u; float f; } v;
  v.u = ((unsigned)u) << 16;
  return v.f;
}

#define MODE_BIAS 1
#define MODE_GELU 2
#define MODE_RES 4
#define MODE_TM 8
#define MODE_OUT16 16
#define MODE_KVT 32
#define MODE_RELU 64
#define MODE_CONVROW 128

// ---------------------------------------------------------------------------
// te: sinusoidal time embedding (2 x 512)
// ---------------------------------------------------------------------------
__global__ void te_k(const float* __restrict__ ts, float* __restrict__ te) {
  int t = threadIdx.x;
  int b = t >> 8, i = t & 255;
  float tv = ts[b];
  float fr = __expf((float)i * (-9.210340371976184f / 255.f));
  float arg = tv * fr;
  te[b * 512 + i] = sinf(arg);
  te[b * 512 + 256 + i] = cosf(arg);
}

// ---------------------------------------------------------------------------
// Split-K M=2 MLP, phase A: partial[l][ks][2][N] over 128-row K-chunks.
// grid = (N/64, K/128, L), 256 threads. Each thread: 8 x float4 streaming
// loads (fully unrolled -> 8 loads in flight), shfl+LDS reduce.
// ---------------------------------------------------------------------------
__global__ __launch_bounds__(256) void mlpA_k(const float* __restrict__ A,
                                              const float* __restrict__ B,
                                              float* __restrict__ part, int K,
                                              int N, long sA, long sB) {
  int l = blockIdx.z;
  const float* Ap = A + (size_t)l * sA;
  const float* Bp = B + (size_t)l * sB;
  int KS = K >> 7;
  int tid = threadIdx.x;
  int c16 = tid & 15;
  int col = blockIdx.x * 64 + c16 * 4;
  int kr = tid >> 4;  // 0..15 : k-row within chunk
  int k0 = blockIdx.y * 128 + kr;
  float4 a0 = {0.f, 0.f, 0.f, 0.f}, a1 = {0.f, 0.f, 0.f, 0.f};
#pragma unroll
  for (int i = 0; i < 8; ++i) {
    int k = k0 + i * 16;
    float4 bv = *(const float4*)&Bp[(size_t)k * N + col];
    float x0 = Ap[k], x1 = Ap[K + k];
    a0.x = fmaf(x0, bv.x, a0.x);
    a0.y = fmaf(x0, bv.y, a0.y);
    a0.z = fmaf(x0, bv.z, a0.z);
    a0.w = fmaf(x0, bv.w, a0.w);
    a1.x = fmaf(x1, bv.x, a1.x);
    a1.y = fmaf(x1, bv.y, a1.y);
    a1.z = fmaf(x1, bv.z, a1.z);
    a1.w = fmaf(x1, bv.w, a1.w);
  }
  // butterfly over lanes {c16, c16+16, c16+32, c16+48}: sums 4 k-rows in wave
#pragma unroll
  for (int off = 16; off < 64; off <<= 1) {
    a0.x += __shfl_xor(a0.x, off);
    a0.y += __shfl_xor(a0.y, off);
    a0.z += __shfl_xor(a0.z, off);
    a0.w += __shfl_xor(a0.w, off);
    a1.x += __shfl_xor(a1.x, off);
    a1.y += __shfl_xor(a1.y, off);
    a1.z += __shfl_xor(a1.z, off);
    a1.w += __shfl_xor(a1.w, off);
  }
  __shared__ float red[4][2][64];
  int w = tid >> 6, lane = tid & 63;
  if (lane < 16) {
    *(float4*)&red[w][0][c16 * 4] = a0;
    *(float4*)&red[w][1][c16 * 4] = a1;
  }
  __syncthreads();
  if (tid < 128) {
    int m = tid >> 6, c = tid & 63;
    float s = red[0][m][c] + red[1][m][c] + red[2][m][c] + red[3][m][c];
    part[(((size_t)l * KS + blockIdx.y) * 2 + m) * N + blockIdx.x * 64 + c] = s;
  }
}

// ---------------------------------------------------------------------------
// Split-K M=2 MLP, phase B: reduce KS partials + bias (+gelu) -> C.
// grid = L*2*N/256. N must be pow2 (512/2048); lgN = log2(N).
// ---------------------------------------------------------------------------
__global__ __launch_bounds__(256) void mlpB_k(const float* __restrict__ part,
                                              const float* __restrict__ bias,
                                              float* __restrict__ C, int N,
                                              int lgN, int KS, int dogelu,
                                              long sb, long sC) {
  int idx = blockIdx.x * 256 + threadIdx.x;
  int col = idx & (N - 1);
  int lm = idx >> lgN;
  int m = lm & 1, l = lm >> 1;
  float s = 0.f;
  for (int ks = 0; ks < KS; ++ks)
    s += part[(((size_t)l * KS + ks) * 2 + m) * N + col];
  s += bias[(size_t)l * sb + col];
  if (dogelu) s = gelu_f(s);
  C[(size_t)l * sC + (size_t)m * N + col] = s;
}

// ---------------------------------------------------------------------------
// conv1: (2,1,1024) -> (2,256,1024), k=7 pad=3, ReLU. buf1[b][co][t] fp32.
// ---------------------------------------------------------------------------
__global__ __launch_bounds__(256) void conv1_k(const float* __restrict__ x,
                                               const float* __restrict__ w1,
                                               const float* __restrict__ b1,
                                               float* __restrict__ buf1) {
  int idx = blockIdx.x * 256 + threadIdx.x;
  int t = idx & 1023, co = (idx >> 10) & 255, b = idx >> 18;
  float acc = b1[co];
#pragma unroll
  for (int k = 0; k < 7; ++k) {
    int gt = t + k - 3;
    if (gt >= 0 && gt < 1024)
      acc = fmaf(w1[co * 7 + k], x[b * 1024 + gt], acc);
  }
  buf1[idx] = fmaxf(acc, 0.f);
}

// ---------------------------------------------------------------------------
// im2col for conv2: buf1[b][ci][t] -> A16[b*1024+t][ci*7+k] bf16 (0-padded)
// ---------------------------------------------------------------------------
__global__ __launch_bounds__(256) void im2col_k(const float* __restrict__ buf1,
                                                u16* __restrict__ A16) {
  int idx = blockIdx.x * 256 + threadIdx.x;  // 2048*1792
  int c = idx % 1792;
  int m = idx / 1792;
  int b = m >> 10, tt = m & 1023;
  int ci = c / 7, k = c - ci * 7;
  int gt = tt + k - 3;
  float v = (gt >= 0 && gt < 1024) ? buf1[((b * 256) + ci) * 1024 + gt] : 0.f;
  A16[idx] = f2b(v);
}

// ---------------------------------------------------------------------------
// copy cond (fp32) into hbuf rows 1024..1087 per batch
// ---------------------------------------------------------------------------
__global__ void cond_k(const float* __restrict__ cond,
                       float* __restrict__ hbuf) {
  int idx = blockIdx.x * 256 + threadIdx.x;  // 65536
  int b = idx >> 15, rem = idx & 32767;
  int j = rem >> 9, cc = rem & 511;
  hbuf[(size_t)(b * 1088 + 1024 + j) * 512 + cc] = cond[idx];
}

// ---------------------------------------------------------------------------
// LayerNorm in-place (fp32) + bf16 copy. grid = 2176 rows.
// ---------------------------------------------------------------------------
__global__ __launch_bounds__(256) void ln_k(float* __restrict__ h,
                                            u16* __restrict__ h16,
                                            const float* __restrict__ g,
                                            const float* __restrict__ bb) {
  int row = blockIdx.x;
  float* p = h + (size_t)row * 512;
  int t = threadIdx.x;
  float x0 = p[t], x1 = p[t + 256];
  float s = x0 + x1, q = x0 * x0 + x1 * x1;
#pragma unroll
  for (int off = 1; off < 64; off <<= 1) {
    s += __shfl_xor(s, off);
    q += __shfl_xor(q, off);
  }
  __shared__ float ps[4], pq[4];
  int w = t >> 6, lane = t & 63;
  if (lane == 0) {
    ps[w] = s;
    pq[w] = q;
  }
  __syncthreads();
  s = ps[0] + ps[1] + ps[2] + ps[3];
  q = pq[0] + pq[1] + pq[2] + pq[3];
  float mean = s * (1.f / 512.f);
  float var = q * (1.f / 512.f) - mean * mean;
  float rs = rsqrtf(var + 1e-5f);
  float v0 = (x0 - mean) * rs * g[t] + bb[t];
  float v1 = (x1 - mean) * rs * g[t + 256] + bb[t + 256];
  p[t] = v0;
  p[t + 256] = v1;
  h16[(size_t)row * 512 + t] = f2b(v0);
  h16[(size_t)row * 512 + t + 256] = f2b(v1);
}

// ---------------------------------------------------------------------------
// Weight convert+transpose tile: src fp32 [K][N] -> dst bf16 [N][K], 64x64.
// ---------------------------------------------------------------------------
__device__ __forceinline__ void wcvt_tile(float (*T)[65],
                                          const float* __restrict__ src,
                                          u16* __restrict__ dst, int K, int N,
                                          int tk, int tn, int t) {
  int kl = t >> 2, nseg = (t & 3) * 16;
#pragma unroll
  for (int j = 0; j < 4; ++j) {
    float4 v =
        *(const float4*)&src[(size_t)(tk * 64 + kl) * N + tn * 64 + nseg + j * 4];
    T[nseg + j * 4 + 0][kl] = v.x;
    T[nseg + j * 4 + 1][kl] = v.y;
    T[nseg + j * 4 + 2][kl] = v.z;
    T[nseg + j * 4 + 3][kl] = v.w;
  }
  __syncthreads();
  int nl = t >> 2, kseg = (t & 3) * 16;
#pragma unroll
  for (int j = 0; j < 4; ++j) {
    ushort4 o;
    o.x = f2b(T[nl][kseg + j * 4 + 0]);
    o.y = f2b(T[nl][kseg + j * 4 + 1]);
    o.z = f2b(T[nl][kseg + j * 4 + 2]);
    o.w = f2b(T[nl][kseg + j * 4 + 3]);
    *(ushort4*)&dst[(size_t)(tn * 64 + nl) * K + tk * 64 + kseg + j * 4] = o;
  }
}

// Converts one layer's 5 weight matrices. grid = 656 tiles.
__global__ __launch_bounds__(256) void wcvt5_k(
    const float* wq, const float* wkv, const float* wo, const float* w1,
    const float* w2, u16* dq, u16* dkv, u16* dwo, u16* d1, u16* d2) {
  __shared__ float T[64][65];
  int bid = blockIdx.x, t = threadIdx.x;
  if (bid < 64) {
    wcvt_tile(T, wq, dq, 512, 512, bid >> 3, bid & 7, t);
  } else if (bid < 80) {
    int id = bid - 64;
    wcvt_tile(T, wkv, dkv, 512, 128, id >> 1, id & 1, t);
  } else if (bid < 144) {
    int id = bid - 80;
    wcvt_tile(T, wo, dwo, 512, 512, id >> 3, id & 7, t);
  } else if (bid < 400) {
    int id = bid - 144;
    wcvt_tile(T, w1, d1, 512, 2048, id >> 5, id & 31, t);
  } else {
    int id = bid - 400;
    wcvt_tile(T, w2, d2, 2048, 512, id >> 3, id & 7, t);
  }
}

// Generic single matrix transpose-convert (for out_w1: 512x1024).
__global__ __launch_bounds__(256) void wcvtT_k(const float* src, u16* dst,
                                               int K, int N) {
  __shared__ float T[64][65];
  int nt = N >> 6;
  int tk = blockIdx.x / nt, tn = blockIdx.x % nt;
  wcvt_tile(T, src, dst, K, N, tk, tn, threadIdx.x);
}

// Flat fp32 -> bf16 cast (conv_w2: already [co][ci*7+k] = [N][K]).
__global__ __launch_bounds__(256) void fcvt_k(const float* __restrict__ src,
                                              u16* __restrict__ dst, int n) {
  int i = (blockIdx.x * 256 + threadIdx.x) * 4;
  if (i >= n) return;
  float4 v = *(const float4*)&src[i];
  ushort4 o;
  o.x = f2b(v.x);
  o.y = f2b(v.y);
  o.z = f2b(v.z);
  o.w = f2b(v.w);
  *(ushort4*)&dst[i] = o;
}

// ---------------------------------------------------------------------------
// bf16 MFMA GEMM: C(MxN) = A(MxK bf16 row-major) @ B^T(N x K bf16 row-major)
// BM x 128 tile, 4 waves (2x2), each 16x16x32 MFMA subtiles. K % 32 == 0.
// ---------------------------------------------------------------------------
template <int BM>
__global__ __launch_bounds__(256) void bgemm_k(
    const u16* __restrict__ A, const u16* __restrict__ B,
    const float* __restrict__ bias, const float* __restrict__ tmv,
    const float* __restrict__ res, float* __restrict__ Cf,
    u16* __restrict__ C16, u16* __restrict__ C16b, int K, int N, int mode) {
  constexpr int SM = (BM == 128) ? 4 : 2;
  __shared__ u16 As[BM * 40];
  __shared__ u16 Bs[128 * 40];
  int t = threadIdx.x;
  int n0 = blockIdx.x * 128, m0 = blockIdx.y * BM;
  int wid = t >> 6, lane = t & 63;
  int quad = lane >> 4, l15 = lane & 15;
  int wm = (wid >> 1) * (BM / 2), wn = (wid & 1) * 64;
  f32x4 acc[SM][4];
#pragma unroll
  for (int i = 0; i < SM; ++i)
#pragma unroll
    for (int j = 0; j < 4; ++j) acc[i][j] = (f32x4){0.f, 0.f, 0.f, 0.f};

  for (int k0 = 0; k0 < K; k0 += 32) {
    // stage A (BM x 32) and B (128 x 32), both k-contiguous rows
    if (BM == 128) {
      int r = t >> 1, hh = (t & 1) * 16;
      const u16* ap = A + (size_t)(m0 + r) * K + k0 + hh;
      *(ushort8*)&As[r * 40 + hh] = *(const ushort8*)ap;
      *(ushort8*)&As[r * 40 + hh + 8] = *(const ushort8*)(ap + 8);
    } else {
      int r = t >> 2, q8 = (t & 3) * 8;
      *(ushort8*)&As[r * 40 + q8] =
          *(const ushort8*)(A + (size_t)(m0 + r) * K + k0 + q8);
    }
    {
      int r = t >> 1, hh = (t & 1) * 16;
      const u16* bp = B + (size_t)(n0 + r) * K + k0 + hh;
      *(ushort8*)&Bs[r * 40 + hh] = *(const ushort8*)bp;
      *(ushort8*)&Bs[r * 40 + hh + 8] = *(const ushort8*)(bp + 8);
    }
    __syncthreads();
    short8 af[SM], bfr[4];
#pragma unroll
    for (int sm = 0; sm < SM; ++sm)
      af[sm] = *(const short8*)&As[(wm + sm * 16 + l15) * 40 + quad * 8];
#pragma unroll
    for (int sn = 0; sn < 4; ++sn)
      bfr[sn] = *(const short8*)&Bs[(wn + sn * 16 + l15) * 40 + quad * 8];
#pragma unroll
    for (int sm = 0; sm < SM; ++sm)
#pragma unroll
      for (int sn = 0; sn < 4; ++sn)
        acc[sm][sn] = MFMA_B16(af[sm], bfr[sn], acc[sm][sn]);
    __syncthreads();
  }

#pragma unroll
  for (int sm = 0; sm < SM; ++sm) {
#pragma unroll
    for (int reg = 0; reg < 4; ++reg) {
      int row = m0 + wm + sm * 16 + quad * 4 + reg;
      int orow = (mode & MODE_CONVROW) ? row + ((row >> 10) << 6) : row;
#pragma unroll
      for (int sn = 0; sn < 4; ++sn) {
        int col = n0 + wn + sn * 16 + l15;
        float v = acc[sm][sn][reg];
        if (mode & MODE_BIAS) v += bias[col];
        if (mode & MODE_TM) v += tmv[(row >= 1088 ? 512 : 0) + col];
        if (mode & MODE_RES) v += res[(size_t)orow * 512 + col];
        if (mode & MODE_GELU) v = gelu_f(v);
        if (mode & MODE_RELU) v = fmaxf(v, 0.f);
        if (mode & MODE_KVT) {
          if (col < 64)
            C16[orow * 64 + col] = f2b(v);
          else
            C16b[(size_t)(col - 64) * 2176 + orow] = f2b(v);
        } else if (mode & MODE_OUT16) {
          C16[(size_t)orow * N + col] = f2b(v);
        } else {
          Cf[(size_t)orow * N + col] = v;
        }
      }
    }
  }
}

// ---------------------------------------------------------------------------
// MFMA flash attention, MQA (1 KV head / 8 Q heads), bf16 in, fp32 accum.
// Block = (qt, h, b): 64 Q rows. K tiles of 64. In-place q16 -> o.
// Wave w owns S/O rows [16w,16w+16); online softmax in registers
// (C-layout: row = quad*4+reg, col = sn*16 + (lane&15)).
// ---------------------------------------------------------------------------
__global__ __launch_bounds__(256) void attn_k(const u16* __restrict__ q,
                                              const u16* __restrict__ k16,
                                              const u16* __restrict__ vT16,
                                              u16* __restrict__ o) {
  __shared__ u16 Qs[64 * 72];
  __shared__ u16 Ks[64 * 72];
  __shared__ u16 VT[64 * 72];
  __shared__ u16 Ps[64 * 72];
  int t = threadIdx.x;
  int qt = blockIdx.x, h = blockIdx.y, b = blockIdx.z;
  int wid = t >> 6, lane = t & 63;
  int quad = lane >> 4, l15 = lane & 15;
  int w16 = wid * 16;
  // stage Q (64 x 64)
  {
    int r = t >> 2, seg = (t & 3) * 16;
    const u16* qp = q + (size_t)(b * 1088 + qt * 64 + r) * 512 + h * 64 + seg;
    *(ushort8*)&Qs[r * 72 + seg] = *(const ushort8*)qp;
    *(ushort8*)&Qs[r * 72 + seg + 8] = *(const ushort8*)(qp + 8);
  }
  f32x4 accO[4];
#pragma unroll
  for (int i = 0; i < 4; ++i) accO[i] = (f32x4){0.f, 0.f, 0.f, 0.f};
  float mi[4] = {-1e30f, -1e30f, -1e30f, -1e30f};
  float li[4] = {0.f, 0.f, 0.f, 0.f};

  for (int kt = 0; kt < 17; ++kt) {
    __syncthreads();
    {
      int r = t >> 2, seg = (t & 3) * 16;
      const u16* kp = k16 + (size_t)(b * 1088 + kt * 64 + r) * 64 + seg;
      *(ushort8*)&Ks[r * 72 + seg] = *(const ushort8*)kp;
      *(ushort8*)&Ks[r * 72 + seg + 8] = *(const ushort8*)(kp + 8);
      const u16* vp = vT16 + (size_t)r * 2176 + b * 1088 + kt * 64 + seg;
      *(ushort8*)&VT[r * 72 + seg] = *(const ushort8*)vp;
      *(ushort8*)&VT[r * 72 + seg + 8] = *(const ushort8*)(vp + 8);
    }
    __syncthreads();
    // S = Q K^T (16 rows x 64 cols per wave)
    f32x4 sc[4];
#pragma unroll
    for (int sn = 0; sn < 4; ++sn) sc[sn] = (f32x4){0.f, 0.f, 0.f, 0.f};
#pragma unroll
    for (int s = 0; s < 2; ++s) {
      short8 a = *(const short8*)&Qs[(w16 + l15) * 72 + s * 32 + quad * 8];
#pragma unroll
      for (int sn = 0; sn < 4; ++sn) {
        short8 bb = *(const short8*)&Ks[(sn * 16 + l15) * 72 + s * 32 + quad * 8];
        sc[sn] = MFMA_B16(a, bb, sc[sn]);
      }
    }
    // online softmax per row (row = w16 + quad*4 + reg)
#pragma unroll
    for (int reg = 0; reg < 4; ++reg) {
      float s0 = sc[0][reg] * 0.125f, s1 = sc[1][reg] * 0.125f;
      float s2 = sc[2][reg] * 0.125f, s3 = sc[3][reg] * 0.125f;
      float mx = fmaxf(fmaxf(s0, s1), fmaxf(s2, s3));
#pragma unroll
      for (int off = 1; off < 16; off <<= 1) mx = fmaxf(mx, __shfl_xor(mx, off));
      float mn = fmaxf(mi[reg], mx);
      float al = __expf(mi[reg] - mn);
      mi[reg] = mn;
      float p0 = __expf(s0 - mn), p1 = __expf(s1 - mn);
      float p2 = __expf(s2 - mn), p3 = __expf(s3 - mn);
      int rr = (w16 + quad * 4 + reg) * 72 + l15;
      Ps[rr] = f2b(p0);
      Ps[rr + 16] = f2b(p1);
      Ps[rr + 32] = f2b(p2);
      Ps[rr + 48] = f2b(p3);
      float psum = p0 + p1 + p2 + p3;
#pragma unroll
      for (int off = 1; off < 16; off <<= 1) psum += __shfl_xor(psum, off);
      li[reg] = li[reg] * al + psum;
#pragma unroll
      for (int sn = 0; sn < 4; ++sn) accO[sn][reg] *= al;
    }
    // O += P V  (P rows are wave-private; compiler inserts lgkm waits)
#pragma unroll
    for (int s = 0; s < 2; ++s) {
      short8 pa = *(const short8*)&Ps[(w16 + l15) * 72 + s * 32 + quad * 8];
#pragma unroll
      for (int sn = 0; sn < 4; ++sn) {
        short8 vb = *(const short8*)&VT[(sn * 16 + l15) * 72 + s * 32 + quad * 8];
        accO[sn] = MFMA_B16(pa, vb, accO[sn]);
      }
    }
  }
  // write O (bf16), in-place over q16
#pragma unroll
  for (int reg = 0; reg < 4; ++reg) {
    float inv = 1.f / li[reg];
    int row = b * 1088 + qt * 64 + w16 + quad * 4 + reg;
#pragma unroll
    for (int sn = 0; sn < 4; ++sn) {
      o[(size_t)row * 512 + h * 64 + sn * 16 + l15] = f2b(accO[sn][reg] * inv);
    }
  }
}

// ---------------------------------------------------------------------------
// Output head matvec: out[b*1024+t] = g16[b*1088+t][0:1024].w2 + b2, fp32.
// ---------------------------------------------------------------------------
__global__ __launch_bounds__(256) void outvec_k(const u16* __restrict__ G,
                                               const float* __restrict__ w,
                                               const float* __restrict__ b2,
                                               float* __restrict__ out) {
  int row = blockIdx.x;  // 0..2047
  int b = row >> 10, tt = row & 1023;
  const u16* g = G + (size_t)(b * 1088 + tt) * 1024;
  int k0 = threadIdx.x * 4;
  ushort4 gv = *(const ushort4*)&g[k0];
  float acc = b2f(gv.x) * w[k0] + b2f(gv.y) * w[k0 + 1] +
              b2f(gv.z) * w[k0 + 2] + b2f(gv.w) * w[k0 + 3];
#pragma unroll
  for (int off = 1; off < 64; off <<= 1) acc += __shfl_xor(acc, off);
  __shared__ float part[4];
  int wv = threadIdx.x >> 6, lane = threadIdx.x & 63;
  if (lane == 0) part[wv] = acc;
  __syncthreads();
  if (threadIdx.x == 0) {
    out[row] = part[0] + part[1] + part[2] + part[3] + b2[0];
  }
}

// ---------------------------------------------------------------------------
extern "C" void kernel_launch(void* const* d_in, const int* in_sizes, int n_in,
                              void* d_out, int out_size, void* d_ws,
                              size_t ws_size, hipStream_t stream) {
  (void)in_sizes;
  (void)n_in;
  (void)out_size;
  (void)ws_size;
  const float* x = (const float*)d_in[0];
  const float* timesteps = (const float*)d_in[1];
  const float* cond = (const float*)d_in[2];
  const float* conv_w1 = (const float*)d_in[3];
  const float* conv_b1 = (const float*)d_in[4];
  const float* conv_w2 = (const float*)d_in[5];
  const float* conv_b2 = (const float*)d_in[6];
  const float* tpe_w1 = (const float*)d_in[7];
  const float* tpe_b1 = (const float*)d_in[8];
  const float* tpe_w2 = (const float*)d_in[9];
  const float* tpe_b2 = (const float*)d_in[10];
  const float* ln1_g = (const float*)d_in[11];
  const float* ln1_b = (const float*)d_in[12];
  const float* wq = (const float*)d_in[13];
  const float* wkv = (const float*)d_in[14];
  const float* wo = (const float*)d_in[15];
  const float* bo = (const float*)d_in[16];
  const float* ln2_g = (const float*)d_in[17];
  const float* ln2_b = (const float*)d_in[18];
  const float* ffn_w1 = (const float*)d_in[19];
  const float* ffn_b1 = (const float*)d_in[20];
  const float* ffn_w2 = (const float*)d_in[21];
  const float* ffn_b2 = (const float*)d_in[22];
  const float* tm_w1 = (const float*)d_in[23];
  const float* tm_b1 = (const float*)d_in[24];
  const float* tm_w2 = (const float*)d_in[25];
  const float* tm_b2 = (const float*)d_in[26];
  const float* fn_g = (const float*)d_in[27];
  const float* fn_b = (const float*)d_in[28];
  const float* out_w1 = (const float*)d_in[29];
  const float* out_b1 = (const float*)d_in[30];
  const float* out_w2 = (const float*)d_in[31];
  const float* out_b2 = (const float*)d_in[32];

  // Workspace layout (float offsets). Total 6,070,272 fl = 24.3 MB.
  float* w = (float*)d_ws;
  float* te = w + 0;
  float* tpe_mid = w + 1024;
  float* time_emb = w + 5120;
  float* tm_mid = w + 6144;
  float* tm = w + 55296;                    // ends 67584
  float* hbuf = w + 131072;                 // 2176x512 fp32, ends 1245184
  u16* q16 = (u16*)(w + 1245184);           // 2176x512 bf16 (557056 fl)
  float* buf1 = w + 1245184;                // conv stage alias (524288 fl)
  u16* hb16 = (u16*)(w + 1802240);          // 2176x512 bf16
  u16* k16 = (u16*)(w + 2359296);           // 2176x64 bf16 (69632 fl)
  u16* vT16 = (u16*)(w + 2428928);          // 64x2176 bf16 (69632 fl)
  u16* mid16 = (u16*)(w + 2498560);         // 2176x2048 bf16 (2228224 fl)
  u16* im16 = mid16;                        // 2048x1792 bf16 (stem alias)
  u16* g16 = mid16;                         // 2176x1024 bf16 (head alias)
  u16* wbuf = (u16*)(w + 4726784);          // 2686976 u16, ends 6070272
  u16* wq16 = wbuf;
  u16* wkv16 = wbuf + 262144;
  u16* wo16 = wbuf + 327680;
  u16* w116 = wbuf + 589824;
  u16* w216 = wbuf + 1638400;
  u16* cw216 = wbuf;    // conv_w2 bf16 (917504), stem alias
  u16* ow116 = wbuf;    // out_w1^T bf16 (524288), head alias
  // split-K partial scratch (<= 196608 fl) -- aliases hbuf, which is first
  // written later by the conv stem (stream-ordered, so no hazard).
  float* part = hbuf;

  // time embedding + time-MLP pipeline (split-K, two-phase)
  te_k<<<1, 512, 0, stream>>>(timesteps, te);
  // tpe1: te(2x512) @ tpe_w1(512x2048) + b, gelu -> tpe_mid
  mlpA_k<<<dim3(32, 4, 1), 256, 0, stream>>>(te, tpe_w1, part, 512, 2048, 0, 0);
  mlpB_k<<<16, 256, 0, stream>>>(part, tpe_b1, tpe_mid, 2048, 11, 4, 1, 0, 0);
  // tpe2: tpe_mid(2x2048) @ tpe_w2(2048x512) + b -> time_emb
  mlpA_k<<<dim3(8, 16, 1), 256, 0, stream>>>(tpe_mid, tpe_w2, part, 2048, 512,
                                             0, 0);
  mlpB_k<<<4, 256, 0, stream>>>(part, tpe_b2, time_emb, 512, 9, 16, 0, 0, 0);
  // tm1 (12 layers): time_emb @ tm_w1[l] + b, gelu -> tm_mid[l]
  mlpA_k<<<dim3(32, 4, 12), 256, 0, stream>>>(time_emb, tm_w1, part, 512, 2048,
                                              0, 512L * 2048);
  mlpB_k<<<192, 256, 0, stream>>>(part, tm_b1, tm_mid, 2048, 11, 4, 1, 2048,
                                  2L * 2048);
  // tm2 (12 layers): tm_mid[l] @ tm_w2[l] + b -> tm[l]
  mlpA_k<<<dim3(8, 16, 12), 256, 0, stream>>>(tm_mid, tm_w2, part, 2048, 512,
                                              2L * 2048, 2048L * 512);
  mlpB_k<<<48, 256, 0, stream>>>(part, tm_b2, tm, 512, 9, 16, 0, 512,
                                 2L * 512);

  // conv stem: conv1 (fp32) -> im2col -> bf16 GEMM (conv2 + relu) -> hbuf
  conv1_k<<<2048, 256, 0, stream>>>(x, conv_w1, conv_b1, buf1);
  fcvt_k<<<896, 256, 0, stream>>>(conv_w2, cw216, 917504);
  im2col_k<<<14336, 256, 0, stream>>>(buf1, im16);
  bgemm_k<64><<<dim3(4, 32), 256, 0, stream>>>(
      im16, cw216, conv_b2, nullptr, nullptr, hbuf, nullptr, nullptr, 1792,
      512, MODE_BIAS | MODE_RELU | MODE_CONVROW);
  cond_k<<<256, 256, 0, stream>>>(cond, hbuf);

  for (int l = 0; l < 12; ++l) {
    wcvt5_k<<<656, 256, 0, stream>>>(
        wq + (size_t)l * 512 * 512, wkv + (size_t)l * 512 * 128,
        wo + (size_t)l * 512 * 512, ffn_w1 + (size_t)l * 512 * 2048,
        ffn_w2 + (size_t)l * 2048 * 512, wq16, wkv16, wo16, w116, w216);
    ln_k<<<2176, 256, 0, stream>>>(hbuf, hb16, ln1_g + l * 512,
                                   ln1_b + l * 512);
    bgemm_k<64><<<dim3(4, 34), 256, 0, stream>>>(hb16, wq16, nullptr, nullptr,
                                                 nullptr, nullptr, q16,
                                                 nullptr, 512, 512, MODE_OUT16);
    bgemm_k<64><<<dim3(1, 34), 256, 0, stream>>>(hb16, wkv16, nullptr, nullptr,
                                                 nullptr, nullptr, k16, vT16,
                                                 512, 128, MODE_KVT);
    attn_k<<<dim3(17, 8, 2), 256, 0, stream>>>(q16, k16, vT16, q16);
    bgemm_k<64><<<dim3(4, 34), 256, 0, stream>>>(
        q16, wo16, bo + l * 512, tm + l * 1024, hbuf, hbuf, nullptr, nullptr,
        512, 512, MODE_BIAS | MODE_TM | MODE_RES);
    ln_k<<<2176, 256, 0, stream>>>(hbuf, hb16, ln2_g + l * 512,
                                   ln2_b + l * 512);
    bgemm_k<128><<<dim3(16, 17), 256, 0, stream>>>(
        hb16, w116, ffn_b1 + l * 2048, nullptr, nullptr, nullptr, mid16,
        nullptr, 512, 2048, MODE_BIAS | MODE_GELU | MODE_OUT16);
    bgemm_k<64><<<dim3(4, 34), 256, 0, stream>>>(
        mid16, w216, ffn_b2 + l * 512, nullptr, hbuf, hbuf, nullptr, nullptr,
        2048, 512, MODE_BIAS | MODE_RES);
  }
  ln_k<<<2176, 256, 0, stream>>>(hbuf, hb16, fn_g, fn_b);
  wcvtT_k<<<128, 256, 0, stream>>>(out_w1, ow116, 512, 1024);
  bgemm_k<64><<<dim3(8, 34), 256, 0, stream>>>(
      hb16, ow116, out_b1, nullptr, nullptr, nullptr, g16, nullptr, 512, 1024,
      MODE_BIAS | MODE_GELU | MODE_OUT16);
  outvec_k<<<2048, 256, 0, stream>>>(g16, out_w2, out_b2, (float*)d_out);
}

// Round 3
// 1986.214 us; speedup vs baseline: 1.7347x; 1.4746x over previous
//
#include <hip/hip_runtime.h>
#include <hip/hip_bf16.h>
#include <math.h>

// ---------------------------------------------------------------------------
// MusicDiffusionTransformer forward, MI355X (gfx950).
// Round 7 (resubmit; round-7 bench was lost to GPU acquisition timeout):
// bgemm2_k — 64x64 tiles (more blocks), split-K via grid.z with fused reduce
// epilogue (bred_k), 2-phase double-buffered LDS pipeline with one barrier
// per 64-K step. Old bgemm_k (136-block, 2-barrier/32K, MfmaUtil 2.9%)
// removed.
// ---------------------------------------------------------------------------

typedef unsigned short u16;
typedef __attribute__((ext_vector_type(8))) short short8;
typedef __attribute__((ext_vector_type(8))) unsigned short ushort8;
typedef __attribute__((ext_vector_type(4))) float f32x4;

#define MFMA_B16(a, b, c) __builtin_amdgcn_mfma_f32_16x16x32_bf16(a, b, c, 0, 0, 0)

__device__ __forceinline__ float gelu_f(float x) {
  return 0.5f * x * (1.f + erff(x * 0.70710678118654752f));
}
__device__ __forceinline__ u16 f2b(float x) {
  union { float f; unsigned u; } v;
  v.f = x;
  unsigned r = (v.u + 0x7FFF + ((v.u >> 16) & 1)) >> 16;
  return (u16)r;
}
__device__ __forceinline__ float b2f(u16 u) {
  union { unsigned u; float f; } v;
  v.u = ((unsigned)u) << 16;
  return v.f;
}

#define MODE_BIAS 1
#define MODE_GELU 2
#define MODE_RES 4
#define MODE_TM 8
#define MODE_OUT16 16
#define MODE_KVT 32
#define MODE_RELU 64
#define MODE_CONVROW 128

// ---------------------------------------------------------------------------
// te: sinusoidal time embedding (2 x 512)
// ---------------------------------------------------------------------------
__global__ void te_k(const float* __restrict__ ts, float* __restrict__ te) {
  int t = threadIdx.x;
  int b = t >> 8, i = t & 255;
  float tv = ts[b];
  float fr = __expf((float)i * (-9.210340371976184f / 255.f));
  float arg = tv * fr;
  te[b * 512 + i] = sinf(arg);
  te[b * 512 + 256 + i] = cosf(arg);
}

// ---------------------------------------------------------------------------
// Split-K M=2 MLP, phase A.
// ---------------------------------------------------------------------------
__global__ __launch_bounds__(256) void mlpA_k(const float* __restrict__ A,
                                              const float* __restrict__ B,
                                              float* __restrict__ part, int K,
                                              int N, long sA, long sB) {
  int l = blockIdx.z;
  const float* Ap = A + (size_t)l * sA;
  const float* Bp = B + (size_t)l * sB;
  int KS = K >> 7;
  int tid = threadIdx.x;
  int c16 = tid & 15;
  int col = blockIdx.x * 64 + c16 * 4;
  int kr = tid >> 4;
  int k0 = blockIdx.y * 128 + kr;
  float4 a0 = {0.f, 0.f, 0.f, 0.f}, a1 = {0.f, 0.f, 0.f, 0.f};
#pragma unroll
  for (int i = 0; i < 8; ++i) {
    int k = k0 + i * 16;
    float4 bv = *(const float4*)&Bp[(size_t)k * N + col];
    float x0 = Ap[k], x1 = Ap[K + k];
    a0.x = fmaf(x0, bv.x, a0.x);
    a0.y = fmaf(x0, bv.y, a0.y);
    a0.z = fmaf(x0, bv.z, a0.z);
    a0.w = fmaf(x0, bv.w, a0.w);
    a1.x = fmaf(x1, bv.x, a1.x);
    a1.y = fmaf(x1, bv.y, a1.y);
    a1.z = fmaf(x1, bv.z, a1.z);
    a1.w = fmaf(x1, bv.w, a1.w);
  }
#pragma unroll
  for (int off = 16; off < 64; off <<= 1) {
    a0.x += __shfl_xor(a0.x, off);
    a0.y += __shfl_xor(a0.y, off);
    a0.z += __shfl_xor(a0.z, off);
    a0.w += __shfl_xor(a0.w, off);
    a1.x += __shfl_xor(a1.x, off);
    a1.y += __shfl_xor(a1.y, off);
    a1.z += __shfl_xor(a1.z, off);
    a1.w += __shfl_xor(a1.w, off);
  }
  __shared__ float red[4][2][64];
  int w = tid >> 6, lane = tid & 63;
  if (lane < 16) {
    *(float4*)&red[w][0][c16 * 4] = a0;
    *(float4*)&red[w][1][c16 * 4] = a1;
  }
  __syncthreads();
  if (tid < 128) {
    int m = tid >> 6, c = tid & 63;
    float s = red[0][m][c] + red[1][m][c] + red[2][m][c] + red[3][m][c];
    part[(((size_t)l * KS + blockIdx.y) * 2 + m) * N + blockIdx.x * 64 + c] = s;
  }
}

// ---------------------------------------------------------------------------
// Split-K M=2 MLP, phase B.
// ---------------------------------------------------------------------------
__global__ __launch_bounds__(256) void mlpB_k(const float* __restrict__ part,
                                              const float* __restrict__ bias,
                                              float* __restrict__ C, int N,
                                              int lgN, int KS, int dogelu,
                                              long sb, long sC) {
  int idx = blockIdx.x * 256 + threadIdx.x;
  int col = idx & (N - 1);
  int lm = idx >> lgN;
  int m = lm & 1, l = lm >> 1;
  float s = 0.f;
  for (int ks = 0; ks < KS; ++ks)
    s += part[(((size_t)l * KS + ks) * 2 + m) * N + col];
  s += bias[(size_t)l * sb + col];
  if (dogelu) s = gelu_f(s);
  C[(size_t)l * sC + (size_t)m * N + col] = s;
}

// ---------------------------------------------------------------------------
// conv1: (2,1,1024) -> (2,256,1024), k=7 pad=3, ReLU. buf1[b][co][t] fp32.
// ---------------------------------------------------------------------------
__global__ __launch_bounds__(256) void conv1_k(const float* __restrict__ x,
                                               const float* __restrict__ w1,
                                               const float* __restrict__ b1,
                                               float* __restrict__ buf1) {
  int idx = blockIdx.x * 256 + threadIdx.x;
  int t = idx & 1023, co = (idx >> 10) & 255, b = idx >> 18;
  float acc = b1[co];
#pragma unroll
  for (int k = 0; k < 7; ++k) {
    int gt = t + k - 3;
    if (gt >= 0 && gt < 1024)
      acc = fmaf(w1[co * 7 + k], x[b * 1024 + gt], acc);
  }
  buf1[idx] = fmaxf(acc, 0.f);
}

// ---------------------------------------------------------------------------
// im2col for conv2: buf1[b][ci][t] -> A16[b*1024+t][ci*7+k] bf16 (0-padded)
// ---------------------------------------------------------------------------
__global__ __launch_bounds__(256) void im2col_k(const float* __restrict__ buf1,
                                                u16* __restrict__ A16) {
  int idx = blockIdx.x * 256 + threadIdx.x;  // 2048*1792
  int c = idx % 1792;
  int m = idx / 1792;
  int b = m >> 10, tt = m & 1023;
  int ci = c / 7, k = c - ci * 7;
  int gt = tt + k - 3;
  float v = (gt >= 0 && gt < 1024) ? buf1[((b * 256) + ci) * 1024 + gt] : 0.f;
  A16[idx] = f2b(v);
}

// ---------------------------------------------------------------------------
// copy cond (fp32) into hbuf rows 1024..1087 per batch
// ---------------------------------------------------------------------------
__global__ void cond_k(const float* __restrict__ cond,
                       float* __restrict__ hbuf) {
  int idx = blockIdx.x * 256 + threadIdx.x;  // 65536
  int b = idx >> 15, rem = idx & 32767;
  int j = rem >> 9, cc = rem & 511;
  hbuf[(size_t)(b * 1088 + 1024 + j) * 512 + cc] = cond[idx];
}

// ---------------------------------------------------------------------------
// LayerNorm in-place (fp32) + bf16 copy. grid = 2176 rows.
// ---------------------------------------------------------------------------
__global__ __launch_bounds__(256) void ln_k(float* __restrict__ h,
                                            u16* __restrict__ h16,
                                            const float* __restrict__ g,
                                            const float* __restrict__ bb) {
  int row = blockIdx.x;
  float* p = h + (size_t)row * 512;
  int t = threadIdx.x;
  float x0 = p[t], x1 = p[t + 256];
  float s = x0 + x1, q = x0 * x0 + x1 * x1;
#pragma unroll
  for (int off = 1; off < 64; off <<= 1) {
    s += __shfl_xor(s, off);
    q += __shfl_xor(q, off);
  }
  __shared__ float ps[4], pq[4];
  int w = t >> 6, lane = t & 63;
  if (lane == 0) {
    ps[w] = s;
    pq[w] = q;
  }
  __syncthreads();
  s = ps[0] + ps[1] + ps[2] + ps[3];
  q = pq[0] + pq[1] + pq[2] + pq[3];
  float mean = s * (1.f / 512.f);
  float var = q * (1.f / 512.f) - mean * mean;
  float rs = rsqrtf(var + 1e-5f);
  float v0 = (x0 - mean) * rs * g[t] + bb[t];
  float v1 = (x1 - mean) * rs * g[t + 256] + bb[t + 256];
  p[t] = v0;
  p[t + 256] = v1;
  h16[(size_t)row * 512 + t] = f2b(v0);
  h16[(size_t)row * 512 + t + 256] = f2b(v1);
}

// ---------------------------------------------------------------------------
// Weight convert+transpose tile: src fp32 [K][N] -> dst bf16 [N][K], 64x64.
// ---------------------------------------------------------------------------
__device__ __forceinline__ void wcvt_tile(float (*T)[65],
                                          const float* __restrict__ src,
                                          u16* __restrict__ dst, int K, int N,
                                          int tk, int tn, int t) {
  int kl = t >> 2, nseg = (t & 3) * 16;
#pragma unroll
  for (int j = 0; j < 4; ++j) {
    float4 v =
        *(const float4*)&src[(size_t)(tk * 64 + kl) * N + tn * 64 + nseg + j * 4];
    T[nseg + j * 4 + 0][kl] = v.x;
    T[nseg + j * 4 + 1][kl] = v.y;
    T[nseg + j * 4 + 2][kl] = v.z;
    T[nseg + j * 4 + 3][kl] = v.w;
  }
  __syncthreads();
  int nl = t >> 2, kseg = (t & 3) * 16;
#pragma unroll
  for (int j = 0; j < 4; ++j) {
    ushort4 o;
    o.x = f2b(T[nl][kseg + j * 4 + 0]);
    o.y = f2b(T[nl][kseg + j * 4 + 1]);
    o.z = f2b(T[nl][kseg + j * 4 + 2]);
    o.w = f2b(T[nl][kseg + j * 4 + 3]);
    *(ushort4*)&dst[(size_t)(tn * 64 + nl) * K + tk * 64 + kseg + j * 4] = o;
  }
}

// Converts one layer's 5 weight matrices. grid = 656 tiles.
__global__ __launch_bounds__(256) void wcvt5_k(
    const float* wq, const float* wkv, const float* wo, const float* w1,
    const float* w2, u16* dq, u16* dkv, u16* dwo, u16* d1, u16* d2) {
  __shared__ float T[64][65];
  int bid = blockIdx.x, t = threadIdx.x;
  if (bid < 64) {
    wcvt_tile(T, wq, dq, 512, 512, bid >> 3, bid & 7, t);
  } else if (bid < 80) {
    int id = bid - 64;
    wcvt_tile(T, wkv, dkv, 512, 128, id >> 1, id & 1, t);
  } else if (bid < 144) {
    int id = bid - 80;
    wcvt_tile(T, wo, dwo, 512, 512, id >> 3, id & 7, t);
  } else if (bid < 400) {
    int id = bid - 144;
    wcvt_tile(T, w1, d1, 512, 2048, id >> 5, id & 31, t);
  } else {
    int id = bid - 400;
    wcvt_tile(T, w2, d2, 2048, 512, id >> 3, id & 7, t);
  }
}

// Generic single matrix transpose-convert (for out_w1: 512x1024).
__global__ __launch_bounds__(256) void wcvtT_k(const float* src, u16* dst,
                                               int K, int N) {
  __shared__ float T[64][65];
  int nt = N >> 6;
  int tk = blockIdx.x / nt, tn = blockIdx.x % nt;
  wcvt_tile(T, src, dst, K, N, tk, tn, threadIdx.x);
}

// Flat fp32 -> bf16 cast (conv_w2: already [co][ci*7+k] = [N][K]).
__global__ __launch_bounds__(256) void fcvt_k(const float* __restrict__ src,
                                              u16* __restrict__ dst, int n) {
  int i = (blockIdx.x * 256 + threadIdx.x) * 4;
  if (i >= n) return;
  float4 v = *(const float4*)&src[i];
  ushort4 o;
  o.x = f2b(v.x);
  o.y = f2b(v.y);
  o.z = f2b(v.z);
  o.w = f2b(v.w);
  *(ushort4*)&dst[i] = o;
}

// ---------------------------------------------------------------------------
// bgemm2: C(MxN) = A(MxK bf16 rm) @ B^T(NxK bf16 rm), 64x64 tile, BK=64,
// 4 waves (2x2) of 32x32. Double-buffered LDS (stride 72), prefetch-to-reg
// issued before compute, ONE barrier per K-step. grid = (N/64, M/64, S).
// S>1: write fp32 partial [kz][M][N] (no epilogue), reduce in bred_k.
// ---------------------------------------------------------------------------
__global__ __launch_bounds__(256) void bgemm2_k(
    const u16* __restrict__ A, const u16* __restrict__ B,
    const float* __restrict__ bias, const float* __restrict__ tmv,
    const float* __restrict__ res, float* __restrict__ Cf,
    u16* __restrict__ C16, u16* __restrict__ C16b, float* __restrict__ part,
    int K, int N, int Kblk, int MN, int mode) {
  __shared__ u16 As[2][64 * 72];
  __shared__ u16 Bs[2][64 * 72];
  int t = threadIdx.x;
  int n0 = blockIdx.x * 64, m0 = blockIdx.y * 64;
  int kz = blockIdx.z;
  int wid = t >> 6, lane = t & 63;
  int quad = lane >> 4, l15 = lane & 15;
  int wr = (wid >> 1) * 32, wc = (wid & 1) * 32;
  int sr = t >> 2, sc = (t & 3) * 16;  // staging: row, col-segment (u16 units)
  const u16* Ap = A + (size_t)(m0 + sr) * K + (size_t)kz * Kblk + sc;
  const u16* Bp = B + (size_t)(n0 + sr) * K + (size_t)kz * Kblk + sc;

  f32x4 acc[2][2];
#pragma unroll
  for (int i = 0; i < 2; ++i)
#pragma unroll
    for (int j = 0; j < 2; ++j) acc[i][j] = (f32x4){0.f, 0.f, 0.f, 0.f};

  int nt = Kblk >> 6;
  // prologue: stage K-step 0
  ushort8 ra0 = *(const ushort8*)Ap;
  ushort8 ra1 = *(const ushort8*)(Ap + 8);
  ushort8 rb0 = *(const ushort8*)Bp;
  ushort8 rb1 = *(const ushort8*)(Bp + 8);
  *(ushort8*)&As[0][sr * 72 + sc] = ra0;
  *(ushort8*)&As[0][sr * 72 + sc + 8] = ra1;
  *(ushort8*)&Bs[0][sr * 72 + sc] = rb0;
  *(ushort8*)&Bs[0][sr * 72 + sc + 8] = rb1;
  __syncthreads();
  int cur = 0;
  for (int tt = 0; tt < nt; ++tt) {
    // issue next K-step's global loads early (latency hides under compute)
    if (tt + 1 < nt) {
      const u16* ap = Ap + (tt + 1) * 64;
      const u16* bp = Bp + (tt + 1) * 64;
      ra0 = *(const ushort8*)ap;
      ra1 = *(const ushort8*)(ap + 8);
      rb0 = *(const ushort8*)bp;
      rb1 = *(const ushort8*)(bp + 8);
    }
    short8 af[2][2], bf[2][2];
#pragma unroll
    for (int s = 0; s < 2; ++s)
#pragma unroll
      for (int i = 0; i < 2; ++i) {
        af[i][s] =
            *(const short8*)&As[cur][(wr + i * 16 + l15) * 72 + s * 32 + quad * 8];
        bf[i][s] =
            *(const short8*)&Bs[cur][(wc + i * 16 + l15) * 72 + s * 32 + quad * 8];
      }
#pragma unroll
    for (int s = 0; s < 2; ++s)
#pragma unroll
      for (int i = 0; i < 2; ++i)
#pragma unroll
        for (int j = 0; j < 2; ++j)
          acc[i][j] = MFMA_B16(af[i][s], bf[j][s], acc[i][j]);
    if (tt + 1 < nt) {
      int nx = cur ^ 1;
      *(ushort8*)&As[nx][sr * 72 + sc] = ra0;
      *(ushort8*)&As[nx][sr * 72 + sc + 8] = ra1;
      *(ushort8*)&Bs[nx][sr * 72 + sc] = rb0;
      *(ushort8*)&Bs[nx][sr * 72 + sc + 8] = rb1;
      __syncthreads();
      cur = nx;
    }
  }

  if (gridDim.z > 1) {
    // split-K: raw fp32 partial, epilogue deferred to bred_k
#pragma unroll
    for (int i = 0; i < 2; ++i)
#pragma unroll
      for (int reg = 0; reg < 4; ++reg) {
        int row = m0 + wr + i * 16 + quad * 4 + reg;
#pragma unroll
        for (int j = 0; j < 2; ++j) {
          int col = n0 + wc + j * 16 + l15;
          part[(size_t)kz * MN + (size_t)row * N + col] = acc[i][j][reg];
        }
      }
    return;
  }

#pragma unroll
  for (int i = 0; i < 2; ++i) {
#pragma unroll
    for (int reg = 0; reg < 4; ++reg) {
      int row = m0 + wr + i * 16 + quad * 4 + reg;
      int orow = (mode & MODE_CONVROW) ? row + ((row >> 10) << 6) : row;
#pragma unroll
      for (int j = 0; j < 2; ++j) {
        int col = n0 + wc + j * 16 + l15;
        float v = acc[i][j][reg];
        if (mode & MODE_BIAS) v += bias[col];
        if (mode & MODE_TM) v += tmv[(row >= 1088 ? 512 : 0) + col];
        if (mode & MODE_RES) v += res[(size_t)orow * 512 + col];
        if (mode & MODE_GELU) v = gelu_f(v);
        if (mode & MODE_RELU) v = fmaxf(v, 0.f);
        if (mode & MODE_KVT) {
          if (col < 64)
            C16[orow * 64 + col] = f2b(v);
          else
            C16b[(size_t)(col - 64) * 2176 + orow] = f2b(v);
        } else if (mode & MODE_OUT16) {
          C16[(size_t)orow * N + col] = f2b(v);
        } else {
          Cf[(size_t)orow * N + col] = v;
        }
      }
    }
  }
}

// ---------------------------------------------------------------------------
// bred: reduce S split-K fp32 partials + fused epilogue. N power of 2.
// grid = MN/1024 blocks x 256 threads, 4 cols (float4) per thread.
// ---------------------------------------------------------------------------
__global__ __launch_bounds__(256) void bred_k(
    const float* __restrict__ part, const float* __restrict__ bias,
    const float* __restrict__ tmv, const float* __restrict__ res,
    float* __restrict__ Cf, u16* __restrict__ C16, u16* __restrict__ C16b,
    int MN, int Nmask, int lgN, int S, int mode) {
  int idx = (blockIdx.x * 256 + threadIdx.x) * 4;
  if (idx >= MN) return;
  int row = idx >> lgN;
  int col = idx & Nmask;
  float4 s = *(const float4*)&part[idx];
  for (int ss = 1; ss < S; ++ss) {
    float4 p = *(const float4*)&part[(size_t)ss * MN + idx];
    s.x += p.x;
    s.y += p.y;
    s.z += p.z;
    s.w += p.w;
  }
  float v[4] = {s.x, s.y, s.z, s.w};
#pragma unroll
  for (int j = 0; j < 4; ++j) {
    float vv = v[j];
    int c = col + j;
    if (mode & MODE_BIAS) vv += bias[c];
    if (mode & MODE_TM) vv += tmv[(row >= 1088 ? 512 : 0) + c];
    if (mode & MODE_RES) vv += res[(size_t)row * 512 + c];
    if (mode & MODE_GELU) vv = gelu_f(vv);
    v[j] = vv;
  }
  if (mode & MODE_KVT) {
    if (col < 64) {
      ushort4 o;
      o.x = f2b(v[0]);
      o.y = f2b(v[1]);
      o.z = f2b(v[2]);
      o.w = f2b(v[3]);
      *(ushort4*)&C16[row * 64 + col] = o;
    } else {
#pragma unroll
      for (int j = 0; j < 4; ++j)
        C16b[(size_t)(col - 64 + j) * 2176 + row] = f2b(v[j]);
    }
  } else if (mode & MODE_OUT16) {
    ushort4 o;
    o.x = f2b(v[0]);
    o.y = f2b(v[1]);
    o.z = f2b(v[2]);
    o.w = f2b(v[3]);
    *(ushort4*)&C16[idx] = o;
  } else {
    float4 o = {v[0], v[1], v[2], v[3]};
    *(float4*)&Cf[idx] = o;
  }
}

// ---------------------------------------------------------------------------
// MFMA flash attention, MQA (1 KV head / 8 Q heads), bf16 in, fp32 accum.
// ---------------------------------------------------------------------------
__global__ __launch_bounds__(256) void attn_k(const u16* __restrict__ q,
                                              const u16* __restrict__ k16,
                                              const u16* __restrict__ vT16,
                                              u16* __restrict__ o) {
  __shared__ u16 Qs[64 * 72];
  __shared__ u16 Ks[64 * 72];
  __shared__ u16 VT[64 * 72];
  __shared__ u16 Ps[64 * 72];
  int t = threadIdx.x;
  int qt = blockIdx.x, h = blockIdx.y, b = blockIdx.z;
  int wid = t >> 6, lane = t & 63;
  int quad = lane >> 4, l15 = lane & 15;
  int w16 = wid * 16;
  {
    int r = t >> 2, seg = (t & 3) * 16;
    const u16* qp = q + (size_t)(b * 1088 + qt * 64 + r) * 512 + h * 64 + seg;
    *(ushort8*)&Qs[r * 72 + seg] = *(const ushort8*)qp;
    *(ushort8*)&Qs[r * 72 + seg + 8] = *(const ushort8*)(qp + 8);
  }
  f32x4 accO[4];
#pragma unroll
  for (int i = 0; i < 4; ++i) accO[i] = (f32x4){0.f, 0.f, 0.f, 0.f};
  float mi[4] = {-1e30f, -1e30f, -1e30f, -1e30f};
  float li[4] = {0.f, 0.f, 0.f, 0.f};

  for (int kt = 0; kt < 17; ++kt) {
    __syncthreads();
    {
      int r = t >> 2, seg = (t & 3) * 16;
      const u16* kp = k16 + (size_t)(b * 1088 + kt * 64 + r) * 64 + seg;
      *(ushort8*)&Ks[r * 72 + seg] = *(const ushort8*)kp;
      *(ushort8*)&Ks[r * 72 + seg + 8] = *(const ushort8*)(kp + 8);
      const u16* vp = vT16 + (size_t)r * 2176 + b * 1088 + kt * 64 + seg;
      *(ushort8*)&VT[r * 72 + seg] = *(const ushort8*)vp;
      *(ushort8*)&VT[r * 72 + seg + 8] = *(const ushort8*)(vp + 8);
    }
    __syncthreads();
    f32x4 sc[4];
#pragma unroll
    for (int sn = 0; sn < 4; ++sn) sc[sn] = (f32x4){0.f, 0.f, 0.f, 0.f};
#pragma unroll
    for (int s = 0; s < 2; ++s) {
      short8 a = *(const short8*)&Qs[(w16 + l15) * 72 + s * 32 + quad * 8];
#pragma unroll
      for (int sn = 0; sn < 4; ++sn) {
        short8 bb = *(const short8*)&Ks[(sn * 16 + l15) * 72 + s * 32 + quad * 8];
        sc[sn] = MFMA_B16(a, bb, sc[sn]);
      }
    }
#pragma unroll
    for (int reg = 0; reg < 4; ++reg) {
      float s0 = sc[0][reg] * 0.125f, s1 = sc[1][reg] * 0.125f;
      float s2 = sc[2][reg] * 0.125f, s3 = sc[3][reg] * 0.125f;
      float mx = fmaxf(fmaxf(s0, s1), fmaxf(s2, s3));
#pragma unroll
      for (int off = 1; off < 16; off <<= 1) mx = fmaxf(mx, __shfl_xor(mx, off));
      float mn = fmaxf(mi[reg], mx);
      float al = __expf(mi[reg] - mn);
      mi[reg] = mn;
      float p0 = __expf(s0 - mn), p1 = __expf(s1 - mn);
      float p2 = __expf(s2 - mn), p3 = __expf(s3 - mn);
      int rr = (w16 + quad * 4 + reg) * 72 + l15;
      Ps[rr] = f2b(p0);
      Ps[rr + 16] = f2b(p1);
      Ps[rr + 32] = f2b(p2);
      Ps[rr + 48] = f2b(p3);
      float psum = p0 + p1 + p2 + p3;
#pragma unroll
      for (int off = 1; off < 16; off <<= 1) psum += __shfl_xor(psum, off);
      li[reg] = li[reg] * al + psum;
#pragma unroll
      for (int sn = 0; sn < 4; ++sn) accO[sn][reg] *= al;
    }
#pragma unroll
    for (int s = 0; s < 2; ++s) {
      short8 pa = *(const short8*)&Ps[(w16 + l15) * 72 + s * 32 + quad * 8];
#pragma unroll
      for (int sn = 0; sn < 4; ++sn) {
        short8 vb = *(const short8*)&VT[(sn * 16 + l15) * 72 + s * 32 + quad * 8];
        accO[sn] = MFMA_B16(pa, vb, accO[sn]);
      }
    }
  }
#pragma unroll
  for (int reg = 0; reg < 4; ++reg) {
    float inv = 1.f / li[reg];
    int row = b * 1088 + qt * 64 + w16 + quad * 4 + reg;
#pragma unroll
    for (int sn = 0; sn < 4; ++sn) {
      o[(size_t)row * 512 + h * 64 + sn * 16 + l15] = f2b(accO[sn][reg] * inv);
    }
  }
}

// ---------------------------------------------------------------------------
// Output head matvec: out[b*1024+t] = g16[b*1088+t][0:1024].w2 + b2, fp32.
// ---------------------------------------------------------------------------
__global__ __launch_bounds__(256) void outvec_k(const u16* __restrict__ G,
                                               const float* __restrict__ w,
                                               const float* __restrict__ b2,
                                               float* __restrict__ out) {
  int row = blockIdx.x;  // 0..2047
  int b = row >> 10, tt = row & 1023;
  const u16* g = G + (size_t)(b * 1088 + tt) * 1024;
  int k0 = threadIdx.x * 4;
  ushort4 gv = *(const ushort4*)&g[k0];
  float acc = b2f(gv.x) * w[k0] + b2f(gv.y) * w[k0 + 1] +
              b2f(gv.z) * w[k0 + 2] + b2f(gv.w) * w[k0 + 3];
#pragma unroll
  for (int off = 1; off < 64; off <<= 1) acc += __shfl_xor(acc, off);
  __shared__ float part[4];
  int wv = threadIdx.x >> 6, lane = threadIdx.x & 63;
  if (lane == 0) part[wv] = acc;
  __syncthreads();
  if (threadIdx.x == 0) {
    out[row] = part[0] + part[1] + part[2] + part[3] + b2[0];
  }
}

// ---------------------------------------------------------------------------
extern "C" void kernel_launch(void* const* d_in, const int* in_sizes, int n_in,
                              void* d_out, int out_size, void* d_ws,
                              size_t ws_size, hipStream_t stream) {
  (void)in_sizes;
  (void)n_in;
  (void)out_size;
  const float* x = (const float*)d_in[0];
  const float* timesteps = (const float*)d_in[1];
  const float* cond = (const float*)d_in[2];
  const float* conv_w1 = (const float*)d_in[3];
  const float* conv_b1 = (const float*)d_in[4];
  const float* conv_w2 = (const float*)d_in[5];
  const float* conv_b2 = (const float*)d_in[6];
  const float* tpe_w1 = (const float*)d_in[7];
  const float* tpe_b1 = (const float*)d_in[8];
  const float* tpe_w2 = (const float*)d_in[9];
  const float* tpe_b2 = (const float*)d_in[10];
  const float* ln1_g = (const float*)d_in[11];
  const float* ln1_b = (const float*)d_in[12];
  const float* wq = (const float*)d_in[13];
  const float* wkv = (const float*)d_in[14];
  const float* wo = (const float*)d_in[15];
  const float* bo = (const float*)d_in[16];
  const float* ln2_g = (const float*)d_in[17];
  const float* ln2_b = (const float*)d_in[18];
  const float* ffn_w1 = (const float*)d_in[19];
  const float* ffn_b1 = (const float*)d_in[20];
  const float* ffn_w2 = (const float*)d_in[21];
  const float* ffn_b2 = (const float*)d_in[22];
  const float* tm_w1 = (const float*)d_in[23];
  const float* tm_b1 = (const float*)d_in[24];
  const float* tm_w2 = (const float*)d_in[25];
  const float* tm_b2 = (const float*)d_in[26];
  const float* fn_g = (const float*)d_in[27];
  const float* fn_b = (const float*)d_in[28];
  const float* out_w1 = (const float*)d_in[29];
  const float* out_b1 = (const float*)d_in[30];
  const float* out_w2 = (const float*)d_in[31];
  const float* out_b2 = (const float*)d_in[32];

  // Workspace layout (float offsets). Base total 6,070,272 fl = 24.3 MB.
  float* w = (float*)d_ws;
  float* te = w + 0;
  float* tpe_mid = w + 1024;
  float* time_emb = w + 5120;
  float* tm_mid = w + 6144;
  float* tm = w + 55296;                    // ends 67584
  float* hbuf = w + 131072;                 // 2176x512 fp32, ends 1245184
  u16* q16 = (u16*)(w + 1245184);           // 2176x512 bf16 (557056 fl)
  float* buf1 = w + 1245184;                // conv stage alias (524288 fl)
  u16* hb16 = (u16*)(w + 1802240);          // 2176x512 bf16
  u16* k16 = (u16*)(w + 2359296);           // 2176x64 bf16 (69632 fl)
  u16* vT16 = (u16*)(w + 2428928);          // 64x2176 bf16 (69632 fl)
  u16* mid16 = (u16*)(w + 2498560);         // 2176x2048 bf16 (2228224 fl)
  u16* im16 = mid16;                        // 2048x1792 bf16 (stem alias)
  u16* g16 = mid16;                         // 2176x1024 bf16 (head alias)
  u16* wbuf = (u16*)(w + 4726784);          // 2686976 u16, ends 6070272
  u16* wq16 = wbuf;
  u16* wkv16 = wbuf + 262144;
  u16* wo16 = wbuf + 327680;
  u16* w116 = wbuf + 589824;
  u16* w216 = wbuf + 1638400;
  u16* cw216 = wbuf;    // conv_w2 bf16 (917504), stem alias
  u16* ow116 = wbuf;    // out_w1^T bf16 (524288), head alias
  // split-K scratch:
  //  - pmlp (M=2 MLPs): aliases hbuf (written later by conv stem).
  //  - pmid (q/kv/wo partials): aliases mid16 region (free until ffn1).
  //  - part2 (ffn2 partials): extra 8.9 MB region, only if ws_size allows.
  float* pmlp = hbuf;
  float* pmid = w + 2498560;
  int big = ws_size >= (size_t)(6070272 + 2228224) * 4 ? 1 : 0;
  float* part2 = w + 6070272;

  // time embedding + time-MLP pipeline (split-K, two-phase)
  te_k<<<1, 512, 0, stream>>>(timesteps, te);
  mlpA_k<<<dim3(32, 4, 1), 256, 0, stream>>>(te, tpe_w1, pmlp, 512, 2048, 0, 0);
  mlpB_k<<<16, 256, 0, stream>>>(pmlp, tpe_b1, tpe_mid, 2048, 11, 4, 1, 0, 0);
  mlpA_k<<<dim3(8, 16, 1), 256, 0, stream>>>(tpe_mid, tpe_w2, pmlp, 2048, 512,
                                             0, 0);
  mlpB_k<<<4, 256, 0, stream>>>(pmlp, tpe_b2, time_emb, 512, 9, 16, 0, 0, 0);
  mlpA_k<<<dim3(32, 4, 12), 256, 0, stream>>>(time_emb, tm_w1, pmlp, 512, 2048,
                                              0, 512L * 2048);
  mlpB_k<<<192, 256, 0, stream>>>(pmlp, tm_b1, tm_mid, 2048, 11, 4, 1, 2048,
                                  2L * 2048);
  mlpA_k<<<dim3(8, 16, 12), 256, 0, stream>>>(tm_mid, tm_w2, pmlp, 2048, 512,
                                              2L * 2048, 2048L * 512);
  mlpB_k<<<48, 256, 0, stream>>>(pmlp, tm_b2, tm, 512, 9, 16, 0, 512,
                                 2L * 512);

  // conv stem: conv1 (fp32) -> im2col -> bf16 GEMM (conv2 + relu) -> hbuf
  conv1_k<<<2048, 256, 0, stream>>>(x, conv_w1, conv_b1, buf1);
  fcvt_k<<<896, 256, 0, stream>>>(conv_w2, cw216, 917504);
  im2col_k<<<14336, 256, 0, stream>>>(buf1, im16);
  bgemm2_k<<<dim3(8, 32, 1), 256, 0, stream>>>(
      im16, cw216, conv_b2, nullptr, nullptr, hbuf, nullptr, nullptr, nullptr,
      1792, 512, 1792, 0, MODE_BIAS | MODE_RELU | MODE_CONVROW);
  cond_k<<<256, 256, 0, stream>>>(cond, hbuf);

  for (int l = 0; l < 12; ++l) {
    wcvt5_k<<<656, 256, 0, stream>>>(
        wq + (size_t)l * 512 * 512, wkv + (size_t)l * 512 * 128,
        wo + (size_t)l * 512 * 512, ffn_w1 + (size_t)l * 512 * 2048,
        ffn_w2 + (size_t)l * 2048 * 512, wq16, wkv16, wo16, w116, w216);
    ln_k<<<2176, 256, 0, stream>>>(hbuf, hb16, ln1_g + l * 512,
                                   ln1_b + l * 512);
    // q = hb16 @ wq^T (split-K 2)
    bgemm2_k<<<dim3(8, 34, 2), 256, 0, stream>>>(
        hb16, wq16, nullptr, nullptr, nullptr, nullptr, nullptr, nullptr,
        pmid, 512, 512, 256, 1114112, 0);
    bred_k<<<1088, 256, 0, stream>>>(pmid, nullptr, nullptr, nullptr, nullptr,
                                     q16, nullptr, 1114112, 511, 9, 2,
                                     MODE_OUT16);
    // kv = hb16 @ wkv^T (split-K 2)
    bgemm2_k<<<dim3(2, 34, 2), 256, 0, stream>>>(
        hb16, wkv16, nullptr, nullptr, nullptr, nullptr, nullptr, nullptr,
        pmid, 512, 128, 256, 278528, 0);
    bred_k<<<272, 256, 0, stream>>>(pmid, nullptr, nullptr, nullptr, nullptr,
                                    k16, vT16, 278528, 127, 7, 2, MODE_KVT);
    attn_k<<<dim3(17, 8, 2), 256, 0, stream>>>(q16, k16, vT16, q16);
    // o = attn @ wo^T + bo + tm + res (split-K 2)
    bgemm2_k<<<dim3(8, 34, 2), 256, 0, stream>>>(
        q16, wo16, nullptr, nullptr, nullptr, nullptr, nullptr, nullptr, pmid,
        512, 512, 256, 1114112, 0);
    bred_k<<<1088, 256, 0, stream>>>(pmid, bo + l * 512, tm + l * 1024, hbuf,
                                     hbuf, nullptr, nullptr, 1114112, 511, 9,
                                     2, MODE_BIAS | MODE_TM | MODE_RES);
    ln_k<<<2176, 256, 0, stream>>>(hbuf, hb16, ln2_g + l * 512,
                                   ln2_b + l * 512);
    // ffn1: N=2048 -> 1088 blocks, no split
    bgemm2_k<<<dim3(32, 34, 1), 256, 0, stream>>>(
        hb16, w116, ffn_b1 + l * 2048, nullptr, nullptr, nullptr, mid16,
        nullptr, nullptr, 512, 2048, 512, 0,
        MODE_BIAS | MODE_GELU | MODE_OUT16);
    // ffn2: K=2048; split-K 2 if workspace allows, else direct
    if (big) {
      bgemm2_k<<<dim3(8, 34, 2), 256, 0, stream>>>(
          mid16, w216, nullptr, nullptr, nullptr, nullptr, nullptr, nullptr,
          part2, 2048, 512, 1024, 1114112, 0);
      bred_k<<<1088, 256, 0, stream>>>(part2, ffn_b2 + l * 512, nullptr, hbuf,
                                       hbuf, nullptr, nullptr, 1114112, 511, 9,
                                       2, MODE_BIAS | MODE_RES);
    } else {
      bgemm2_k<<<dim3(8, 34, 1), 256, 0, stream>>>(
          mid16, w216, ffn_b2 + l * 512, nullptr, hbuf, hbuf, nullptr,
          nullptr, nullptr, 2048, 512, 2048, 0, MODE_BIAS | MODE_RES);
    }
  }
  ln_k<<<2176, 256, 0, stream>>>(hbuf, hb16, fn_g, fn_b);
  wcvtT_k<<<128, 256, 0, stream>>>(out_w1, ow116, 512, 1024);
  bgemm2_k<<<dim3(16, 34, 1), 256, 0, stream>>>(
      hb16, ow116, out_b1, nullptr, nullptr, nullptr, g16, nullptr, nullptr,
      512, 1024, 512, 0, MODE_BIAS | MODE_GELU | MODE_OUT16);
  outvec_k<<<2048, 256, 0, stream>>>(g16, out_w2, out_b2, (float*)d_out);
}

// Round 4
// 1860.394 us; speedup vs baseline: 1.8520x; 1.0676x over previous
//
#include <hip/hip_runtime.h>
#include <hip/hip_bf16.h>
#include <math.h>

// ---------------------------------------------------------------------------
// MusicDiffusionTransformer forward, MI355X (gfx950).
// Round 8: attention rework. Old attn_k was latency-bound (272 blocks = 1
// block/CU, serial stage->barrier->MFMA->softmax loop, MfmaUtil 3.6%,
// Occupancy 10.7%). New attn2_k: KV-split S=2 (544 blocks, half the serial
// loop) + double-buffered K/V staging with register prefetch and ONE barrier
// per tile; partial (O_norm bf16, m, l) merged by amerge_k.
// ---------------------------------------------------------------------------

typedef unsigned short u16;
typedef __attribute__((ext_vector_type(8))) short short8;
typedef __attribute__((ext_vector_type(8))) unsigned short ushort8;
typedef __attribute__((ext_vector_type(4))) float f32x4;

#define MFMA_B16(a, b, c) __builtin_amdgcn_mfma_f32_16x16x32_bf16(a, b, c, 0, 0, 0)

__device__ __forceinline__ float gelu_f(float x) {
  return 0.5f * x * (1.f + erff(x * 0.70710678118654752f));
}
__device__ __forceinline__ u16 f2b(float x) {
  union { float f; unsigned u; } v;
  v.f = x;
  unsigned r = (v.u + 0x7FFF + ((v.u >> 16) & 1)) >> 16;
  return (u16)r;
}
__device__ __forceinline__ float b2f(u16 u) {
  union { unsigned u; float f; } v;
  v.u = ((unsigned)u) << 16;
  return v.f;
}

#define MODE_BIAS 1
#define MODE_GELU 2
#define MODE_RES 4
#define MODE_TM 8
#define MODE_OUT16 16
#define MODE_KVT 32
#define MODE_RELU 64
#define MODE_CONVROW 128

// ---------------------------------------------------------------------------
// te: sinusoidal time embedding (2 x 512)
// ---------------------------------------------------------------------------
__global__ void te_k(const float* __restrict__ ts, float* __restrict__ te) {
  int t = threadIdx.x;
  int b = t >> 8, i = t & 255;
  float tv = ts[b];
  float fr = __expf((float)i * (-9.210340371976184f / 255.f));
  float arg = tv * fr;
  te[b * 512 + i] = sinf(arg);
  te[b * 512 + 256 + i] = cosf(arg);
}

// ---------------------------------------------------------------------------
// Split-K M=2 MLP, phase A.
// ---------------------------------------------------------------------------
__global__ __launch_bounds__(256) void mlpA_k(const float* __restrict__ A,
                                              const float* __restrict__ B,
                                              float* __restrict__ part, int K,
                                              int N, long sA, long sB) {
  int l = blockIdx.z;
  const float* Ap = A + (size_t)l * sA;
  const float* Bp = B + (size_t)l * sB;
  int KS = K >> 7;
  int tid = threadIdx.x;
  int c16 = tid & 15;
  int col = blockIdx.x * 64 + c16 * 4;
  int kr = tid >> 4;
  int k0 = blockIdx.y * 128 + kr;
  float4 a0 = {0.f, 0.f, 0.f, 0.f}, a1 = {0.f, 0.f, 0.f, 0.f};
#pragma unroll
  for (int i = 0; i < 8; ++i) {
    int k = k0 + i * 16;
    float4 bv = *(const float4*)&Bp[(size_t)k * N + col];
    float x0 = Ap[k], x1 = Ap[K + k];
    a0.x = fmaf(x0, bv.x, a0.x);
    a0.y = fmaf(x0, bv.y, a0.y);
    a0.z = fmaf(x0, bv.z, a0.z);
    a0.w = fmaf(x0, bv.w, a0.w);
    a1.x = fmaf(x1, bv.x, a1.x);
    a1.y = fmaf(x1, bv.y, a1.y);
    a1.z = fmaf(x1, bv.z, a1.z);
    a1.w = fmaf(x1, bv.w, a1.w);
  }
#pragma unroll
  for (int off = 16; off < 64; off <<= 1) {
    a0.x += __shfl_xor(a0.x, off);
    a0.y += __shfl_xor(a0.y, off);
    a0.z += __shfl_xor(a0.z, off);
    a0.w += __shfl_xor(a0.w, off);
    a1.x += __shfl_xor(a1.x, off);
    a1.y += __shfl_xor(a1.y, off);
    a1.z += __shfl_xor(a1.z, off);
    a1.w += __shfl_xor(a1.w, off);
  }
  __shared__ float red[4][2][64];
  int w = tid >> 6, lane = tid & 63;
  if (lane < 16) {
    *(float4*)&red[w][0][c16 * 4] = a0;
    *(float4*)&red[w][1][c16 * 4] = a1;
  }
  __syncthreads();
  if (tid < 128) {
    int m = tid >> 6, c = tid & 63;
    float s = red[0][m][c] + red[1][m][c] + red[2][m][c] + red[3][m][c];
    part[(((size_t)l * KS + blockIdx.y) * 2 + m) * N + blockIdx.x * 64 + c] = s;
  }
}

// ---------------------------------------------------------------------------
// Split-K M=2 MLP, phase B.
// ---------------------------------------------------------------------------
__global__ __launch_bounds__(256) void mlpB_k(const float* __restrict__ part,
                                              const float* __restrict__ bias,
                                              float* __restrict__ C, int N,
                                              int lgN, int KS, int dogelu,
                                              long sb, long sC) {
  int idx = blockIdx.x * 256 + threadIdx.x;
  int col = idx & (N - 1);
  int lm = idx >> lgN;
  int m = lm & 1, l = lm >> 1;
  float s = 0.f;
  for (int ks = 0; ks < KS; ++ks)
    s += part[(((size_t)l * KS + ks) * 2 + m) * N + col];
  s += bias[(size_t)l * sb + col];
  if (dogelu) s = gelu_f(s);
  C[(size_t)l * sC + (size_t)m * N + col] = s;
}

// ---------------------------------------------------------------------------
// conv1: (2,1,1024) -> (2,256,1024), k=7 pad=3, ReLU. buf1[b][co][t] fp32.
// ---------------------------------------------------------------------------
__global__ __launch_bounds__(256) void conv1_k(const float* __restrict__ x,
                                               const float* __restrict__ w1,
                                               const float* __restrict__ b1,
                                               float* __restrict__ buf1) {
  int idx = blockIdx.x * 256 + threadIdx.x;
  int t = idx & 1023, co = (idx >> 10) & 255, b = idx >> 18;
  float acc = b1[co];
#pragma unroll
  for (int k = 0; k < 7; ++k) {
    int gt = t + k - 3;
    if (gt >= 0 && gt < 1024)
      acc = fmaf(w1[co * 7 + k], x[b * 1024 + gt], acc);
  }
  buf1[idx] = fmaxf(acc, 0.f);
}

// ---------------------------------------------------------------------------
// im2col for conv2: buf1[b][ci][t] -> A16[b*1024+t][ci*7+k] bf16 (0-padded)
// ---------------------------------------------------------------------------
__global__ __launch_bounds__(256) void im2col_k(const float* __restrict__ buf1,
                                                u16* __restrict__ A16) {
  int idx = blockIdx.x * 256 + threadIdx.x;  // 2048*1792
  int c = idx % 1792;
  int m = idx / 1792;
  int b = m >> 10, tt = m & 1023;
  int ci = c / 7, k = c - ci * 7;
  int gt = tt + k - 3;
  float v = (gt >= 0 && gt < 1024) ? buf1[((b * 256) + ci) * 1024 + gt] : 0.f;
  A16[idx] = f2b(v);
}

// ---------------------------------------------------------------------------
// copy cond (fp32) into hbuf rows 1024..1087 per batch
// ---------------------------------------------------------------------------
__global__ void cond_k(const float* __restrict__ cond,
                       float* __restrict__ hbuf) {
  int idx = blockIdx.x * 256 + threadIdx.x;  // 65536
  int b = idx >> 15, rem = idx & 32767;
  int j = rem >> 9, cc = rem & 511;
  hbuf[(size_t)(b * 1088 + 1024 + j) * 512 + cc] = cond[idx];
}

// ---------------------------------------------------------------------------
// LayerNorm in-place (fp32) + bf16 copy. grid = 2176 rows.
// ---------------------------------------------------------------------------
__global__ __launch_bounds__(256) void ln_k(float* __restrict__ h,
                                            u16* __restrict__ h16,
                                            const float* __restrict__ g,
                                            const float* __restrict__ bb) {
  int row = blockIdx.x;
  float* p = h + (size_t)row * 512;
  int t = threadIdx.x;
  float x0 = p[t], x1 = p[t + 256];
  float s = x0 + x1, q = x0 * x0 + x1 * x1;
#pragma unroll
  for (int off = 1; off < 64; off <<= 1) {
    s += __shfl_xor(s, off);
    q += __shfl_xor(q, off);
  }
  __shared__ float ps[4], pq[4];
  int w = t >> 6, lane = t & 63;
  if (lane == 0) {
    ps[w] = s;
    pq[w] = q;
  }
  __syncthreads();
  s = ps[0] + ps[1] + ps[2] + ps[3];
  q = pq[0] + pq[1] + pq[2] + pq[3];
  float mean = s * (1.f / 512.f);
  float var = q * (1.f / 512.f) - mean * mean;
  float rs = rsqrtf(var + 1e-5f);
  float v0 = (x0 - mean) * rs * g[t] + bb[t];
  float v1 = (x1 - mean) * rs * g[t + 256] + bb[t + 256];
  p[t] = v0;
  p[t + 256] = v1;
  h16[(size_t)row * 512 + t] = f2b(v0);
  h16[(size_t)row * 512 + t + 256] = f2b(v1);
}

// ---------------------------------------------------------------------------
// Weight convert+transpose tile: src fp32 [K][N] -> dst bf16 [N][K], 64x64.
// ---------------------------------------------------------------------------
__device__ __forceinline__ void wcvt_tile(float (*T)[65],
                                          const float* __restrict__ src,
                                          u16* __restrict__ dst, int K, int N,
                                          int tk, int tn, int t) {
  int kl = t >> 2, nseg = (t & 3) * 16;
#pragma unroll
  for (int j = 0; j < 4; ++j) {
    float4 v =
        *(const float4*)&src[(size_t)(tk * 64 + kl) * N + tn * 64 + nseg + j * 4];
    T[nseg + j * 4 + 0][kl] = v.x;
    T[nseg + j * 4 + 1][kl] = v.y;
    T[nseg + j * 4 + 2][kl] = v.z;
    T[nseg + j * 4 + 3][kl] = v.w;
  }
  __syncthreads();
  int nl = t >> 2, kseg = (t & 3) * 16;
#pragma unroll
  for (int j = 0; j < 4; ++j) {
    ushort4 o;
    o.x = f2b(T[nl][kseg + j * 4 + 0]);
    o.y = f2b(T[nl][kseg + j * 4 + 1]);
    o.z = f2b(T[nl][kseg + j * 4 + 2]);
    o.w = f2b(T[nl][kseg + j * 4 + 3]);
    *(ushort4*)&dst[(size_t)(tn * 64 + nl) * K + tk * 64 + kseg + j * 4] = o;
  }
}

// Converts one layer's 5 weight matrices. grid = 656 tiles.
__global__ __launch_bounds__(256) void wcvt5_k(
    const float* wq, const float* wkv, const float* wo, const float* w1,
    const float* w2, u16* dq, u16* dkv, u16* dwo, u16* d1, u16* d2) {
  __shared__ float T[64][65];
  int bid = blockIdx.x, t = threadIdx.x;
  if (bid < 64) {
    wcvt_tile(T, wq, dq, 512, 512, bid >> 3, bid & 7, t);
  } else if (bid < 80) {
    int id = bid - 64;
    wcvt_tile(T, wkv, dkv, 512, 128, id >> 1, id & 1, t);
  } else if (bid < 144) {
    int id = bid - 80;
    wcvt_tile(T, wo, dwo, 512, 512, id >> 3, id & 7, t);
  } else if (bid < 400) {
    int id = bid - 144;
    wcvt_tile(T, w1, d1, 512, 2048, id >> 5, id & 31, t);
  } else {
    int id = bid - 400;
    wcvt_tile(T, w2, d2, 2048, 512, id >> 3, id & 7, t);
  }
}

// Generic single matrix transpose-convert (for out_w1: 512x1024).
__global__ __launch_bounds__(256) void wcvtT_k(const float* src, u16* dst,
                                               int K, int N) {
  __shared__ float T[64][65];
  int nt = N >> 6;
  int tk = blockIdx.x / nt, tn = blockIdx.x % nt;
  wcvt_tile(T, src, dst, K, N, tk, tn, threadIdx.x);
}

// Flat fp32 -> bf16 cast (conv_w2: already [co][ci*7+k] = [N][K]).
__global__ __launch_bounds__(256) void fcvt_k(const float* __restrict__ src,
                                              u16* __restrict__ dst, int n) {
  int i = (blockIdx.x * 256 + threadIdx.x) * 4;
  if (i >= n) return;
  float4 v = *(const float4*)&src[i];
  ushort4 o;
  o.x = f2b(v.x);
  o.y = f2b(v.y);
  o.z = f2b(v.z);
  o.w = f2b(v.w);
  *(ushort4*)&dst[i] = o;
}

// ---------------------------------------------------------------------------
// bgemm2: C(MxN) = A(MxK bf16 rm) @ B^T(NxK bf16 rm), 64x64 tile, BK=64,
// 4 waves (2x2) of 32x32. Double-buffered LDS (stride 72), prefetch-to-reg
// issued before compute, ONE barrier per K-step. grid = (N/64, M/64, S).
// S>1: write fp32 partial [kz][M][N] (no epilogue), reduce in bred_k.
// ---------------------------------------------------------------------------
__global__ __launch_bounds__(256) void bgemm2_k(
    const u16* __restrict__ A, const u16* __restrict__ B,
    const float* __restrict__ bias, const float* __restrict__ tmv,
    const float* __restrict__ res, float* __restrict__ Cf,
    u16* __restrict__ C16, u16* __restrict__ C16b, float* __restrict__ part,
    int K, int N, int Kblk, int MN, int mode) {
  __shared__ u16 As[2][64 * 72];
  __shared__ u16 Bs[2][64 * 72];
  int t = threadIdx.x;
  int n0 = blockIdx.x * 64, m0 = blockIdx.y * 64;
  int kz = blockIdx.z;
  int wid = t >> 6, lane = t & 63;
  int quad = lane >> 4, l15 = lane & 15;
  int wr = (wid >> 1) * 32, wc = (wid & 1) * 32;
  int sr = t >> 2, sc = (t & 3) * 16;  // staging: row, col-segment (u16 units)
  const u16* Ap = A + (size_t)(m0 + sr) * K + (size_t)kz * Kblk + sc;
  const u16* Bp = B + (size_t)(n0 + sr) * K + (size_t)kz * Kblk + sc;

  f32x4 acc[2][2];
#pragma unroll
  for (int i = 0; i < 2; ++i)
#pragma unroll
    for (int j = 0; j < 2; ++j) acc[i][j] = (f32x4){0.f, 0.f, 0.f, 0.f};

  int nt = Kblk >> 6;
  // prologue: stage K-step 0
  ushort8 ra0 = *(const ushort8*)Ap;
  ushort8 ra1 = *(const ushort8*)(Ap + 8);
  ushort8 rb0 = *(const ushort8*)Bp;
  ushort8 rb1 = *(const ushort8*)(Bp + 8);
  *(ushort8*)&As[0][sr * 72 + sc] = ra0;
  *(ushort8*)&As[0][sr * 72 + sc + 8] = ra1;
  *(ushort8*)&Bs[0][sr * 72 + sc] = rb0;
  *(ushort8*)&Bs[0][sr * 72 + sc + 8] = rb1;
  __syncthreads();
  int cur = 0;
  for (int tt = 0; tt < nt; ++tt) {
    // issue next K-step's global loads early (latency hides under compute)
    if (tt + 1 < nt) {
      const u16* ap = Ap + (tt + 1) * 64;
      const u16* bp = Bp + (tt + 1) * 64;
      ra0 = *(const ushort8*)ap;
      ra1 = *(const ushort8*)(ap + 8);
      rb0 = *(const ushort8*)bp;
      rb1 = *(const ushort8*)(bp + 8);
    }
    short8 af[2][2], bf[2][2];
#pragma unroll
    for (int s = 0; s < 2; ++s)
#pragma unroll
      for (int i = 0; i < 2; ++i) {
        af[i][s] =
            *(const short8*)&As[cur][(wr + i * 16 + l15) * 72 + s * 32 + quad * 8];
        bf[i][s] =
            *(const short8*)&Bs[cur][(wc + i * 16 + l15) * 72 + s * 32 + quad * 8];
      }
#pragma unroll
    for (int s = 0; s < 2; ++s)
#pragma unroll
      for (int i = 0; i < 2; ++i)
#pragma unroll
        for (int j = 0; j < 2; ++j)
          acc[i][j] = MFMA_B16(af[i][s], bf[j][s], acc[i][j]);
    if (tt + 1 < nt) {
      int nx = cur ^ 1;
      *(ushort8*)&As[nx][sr * 72 + sc] = ra0;
      *(ushort8*)&As[nx][sr * 72 + sc + 8] = ra1;
      *(ushort8*)&Bs[nx][sr * 72 + sc] = rb0;
      *(ushort8*)&Bs[nx][sr * 72 + sc + 8] = rb1;
      __syncthreads();
      cur = nx;
    }
  }

  if (gridDim.z > 1) {
    // split-K: raw fp32 partial, epilogue deferred to bred_k
#pragma unroll
    for (int i = 0; i < 2; ++i)
#pragma unroll
      for (int reg = 0; reg < 4; ++reg) {
        int row = m0 + wr + i * 16 + quad * 4 + reg;
#pragma unroll
        for (int j = 0; j < 2; ++j) {
          int col = n0 + wc + j * 16 + l15;
          part[(size_t)kz * MN + (size_t)row * N + col] = acc[i][j][reg];
        }
      }
    return;
  }

#pragma unroll
  for (int i = 0; i < 2; ++i) {
#pragma unroll
    for (int reg = 0; reg < 4; ++reg) {
      int row = m0 + wr + i * 16 + quad * 4 + reg;
      int orow = (mode & MODE_CONVROW) ? row + ((row >> 10) << 6) : row;
#pragma unroll
      for (int j = 0; j < 2; ++j) {
        int col = n0 + wc + j * 16 + l15;
        float v = acc[i][j][reg];
        if (mode & MODE_BIAS) v += bias[col];
        if (mode & MODE_TM) v += tmv[(row >= 1088 ? 512 : 0) + col];
        if (mode & MODE_RES) v += res[(size_t)orow * 512 + col];
        if (mode & MODE_GELU) v = gelu_f(v);
        if (mode & MODE_RELU) v = fmaxf(v, 0.f);
        if (mode & MODE_KVT) {
          if (col < 64)
            C16[orow * 64 + col] = f2b(v);
          else
            C16b[(size_t)(col - 64) * 2176 + orow] = f2b(v);
        } else if (mode & MODE_OUT16) {
          C16[(size_t)orow * N + col] = f2b(v);
        } else {
          Cf[(size_t)orow * N + col] = v;
        }
      }
    }
  }
}

// ---------------------------------------------------------------------------
// bred: reduce S split-K fp32 partials + fused epilogue. N power of 2.
// grid = MN/1024 blocks x 256 threads, 4 cols (float4) per thread.
// ---------------------------------------------------------------------------
__global__ __launch_bounds__(256) void bred_k(
    const float* __restrict__ part, const float* __restrict__ bias,
    const float* __restrict__ tmv, const float* __restrict__ res,
    float* __restrict__ Cf, u16* __restrict__ C16, u16* __restrict__ C16b,
    int MN, int Nmask, int lgN, int S, int mode) {
  int idx = (blockIdx.x * 256 + threadIdx.x) * 4;
  if (idx >= MN) return;
  int row = idx >> lgN;
  int col = idx & Nmask;
  float4 s = *(const float4*)&part[idx];
  for (int ss = 1; ss < S; ++ss) {
    float4 p = *(const float4*)&part[(size_t)ss * MN + idx];
    s.x += p.x;
    s.y += p.y;
    s.z += p.z;
    s.w += p.w;
  }
  float v[4] = {s.x, s.y, s.z, s.w};
#pragma unroll
  for (int j = 0; j < 4; ++j) {
    float vv = v[j];
    int c = col + j;
    if (mode & MODE_BIAS) vv += bias[c];
    if (mode & MODE_TM) vv += tmv[(row >= 1088 ? 512 : 0) + c];
    if (mode & MODE_RES) vv += res[(size_t)row * 512 + c];
    if (mode & MODE_GELU) vv = gelu_f(vv);
    v[j] = vv;
  }
  if (mode & MODE_KVT) {
    if (col < 64) {
      ushort4 o;
      o.x = f2b(v[0]);
      o.y = f2b(v[1]);
      o.z = f2b(v[2]);
      o.w = f2b(v[3]);
      *(ushort4*)&C16[row * 64 + col] = o;
    } else {
#pragma unroll
      for (int j = 0; j < 4; ++j)
        C16b[(size_t)(col - 64 + j) * 2176 + row] = f2b(v[j]);
    }
  } else if (mode & MODE_OUT16) {
    ushort4 o;
    o.x = f2b(v[0]);
    o.y = f2b(v[1]);
    o.z = f2b(v[2]);
    o.w = f2b(v[3]);
    *(ushort4*)&C16[idx] = o;
  } else {
    float4 o = {v[0], v[1], v[2], v[3]};
    *(float4*)&Cf[idx] = o;
  }
}

// ---------------------------------------------------------------------------
// attn2: MFMA flash attention with KV-split (S=2) + double-buffered K/V
// staging. MQA (1 KV head / 8 Q heads), bf16 in, fp32 accum.
// grid = (17 qt, 8 h, 2 b x 2 s). Split s covers KV tiles [9s, 9s+9-s).
// Writes normalized partial O (bf16) + per-row (m, l) fp32; amerge_k merges.
// ---------------------------------------------------------------------------
__global__ __launch_bounds__(256) void attn2_k(const u16* __restrict__ q,
                                               const u16* __restrict__ k16,
                                               const u16* __restrict__ vT16,
                                               u16* __restrict__ opart,
                                               float* __restrict__ ml) {
  __shared__ u16 Qs[64 * 72];
  __shared__ u16 Ks[2][64 * 72];
  __shared__ u16 VT[2][64 * 72];
  __shared__ u16 Ps[64 * 72];
  int t = threadIdx.x;
  int qt = blockIdx.x, h = blockIdx.y;
  int b = blockIdx.z >> 1, s = blockIdx.z & 1;
  int kt0 = s * 9;
  int ktn = 9 - s;  // 9 tiles for s=0, 8 for s=1 (17 total)
  int wid = t >> 6, lane = t & 63;
  int quad = lane >> 4, l15 = lane & 15;
  int w16 = wid * 16;
  int r = t >> 2, seg = (t & 3) * 16;
  // stage Q (64 x 64)
  {
    const u16* qp = q + (size_t)(b * 1088 + qt * 64 + r) * 512 + h * 64 + seg;
    *(ushort8*)&Qs[r * 72 + seg] = *(const ushort8*)qp;
    *(ushort8*)&Qs[r * 72 + seg + 8] = *(const ushort8*)(qp + 8);
  }
  // prologue: stage K/V tile kt0 into buffer 0
  const u16* kbase = k16 + (size_t)(b * 1088 + kt0 * 64 + r) * 64 + seg;
  const u16* vbase = vT16 + (size_t)r * 2176 + b * 1088 + kt0 * 64 + seg;
  *(ushort8*)&Ks[0][r * 72 + seg] = *(const ushort8*)kbase;
  *(ushort8*)&Ks[0][r * 72 + seg + 8] = *(const ushort8*)(kbase + 8);
  *(ushort8*)&VT[0][r * 72 + seg] = *(const ushort8*)vbase;
  *(ushort8*)&VT[0][r * 72 + seg + 8] = *(const ushort8*)(vbase + 8);
  __syncthreads();

  f32x4 accO[4];
#pragma unroll
  for (int i = 0; i < 4; ++i) accO[i] = (f32x4){0.f, 0.f, 0.f, 0.f};
  float mi[4] = {-1e30f, -1e30f, -1e30f, -1e30f};
  float li[4] = {0.f, 0.f, 0.f, 0.f};

  int cur = 0;
  ushort8 rk0, rk1, rv0, rv1;
  for (int kt = 0; kt < ktn; ++kt) {
    // prefetch next K/V tile into registers (hides L2/HBM latency)
    if (kt + 1 < ktn) {
      const u16* kp = kbase + (size_t)(kt + 1) * 64 * 64;
      const u16* vp = vbase + (kt + 1) * 64;
      rk0 = *(const ushort8*)kp;
      rk1 = *(const ushort8*)(kp + 8);
      rv0 = *(const ushort8*)vp;
      rv1 = *(const ushort8*)(vp + 8);
    }
    // S = Q K^T (16 rows x 64 cols per wave)
    f32x4 sc[4];
#pragma unroll
    for (int sn = 0; sn < 4; ++sn) sc[sn] = (f32x4){0.f, 0.f, 0.f, 0.f};
#pragma unroll
    for (int ss = 0; ss < 2; ++ss) {
      short8 a = *(const short8*)&Qs[(w16 + l15) * 72 + ss * 32 + quad * 8];
#pragma unroll
      for (int sn = 0; sn < 4; ++sn) {
        short8 bb =
            *(const short8*)&Ks[cur][(sn * 16 + l15) * 72 + ss * 32 + quad * 8];
        sc[sn] = MFMA_B16(a, bb, sc[sn]);
      }
    }
    // online softmax per row (row = w16 + quad*4 + reg)
#pragma unroll
    for (int reg = 0; reg < 4; ++reg) {
      float s0 = sc[0][reg] * 0.125f, s1 = sc[1][reg] * 0.125f;
      float s2 = sc[2][reg] * 0.125f, s3 = sc[3][reg] * 0.125f;
      float mx = fmaxf(fmaxf(s0, s1), fmaxf(s2, s3));
#pragma unroll
      for (int off = 1; off < 16; off <<= 1) mx = fmaxf(mx, __shfl_xor(mx, off));
      float mn = fmaxf(mi[reg], mx);
      float al = __expf(mi[reg] - mn);
      mi[reg] = mn;
      float p0 = __expf(s0 - mn), p1 = __expf(s1 - mn);
      float p2 = __expf(s2 - mn), p3 = __expf(s3 - mn);
      int rr = (w16 + quad * 4 + reg) * 72 + l15;
      Ps[rr] = f2b(p0);
      Ps[rr + 16] = f2b(p1);
      Ps[rr + 32] = f2b(p2);
      Ps[rr + 48] = f2b(p3);
      float psum = p0 + p1 + p2 + p3;
#pragma unroll
      for (int off = 1; off < 16; off <<= 1) psum += __shfl_xor(psum, off);
      li[reg] = li[reg] * al + psum;
#pragma unroll
      for (int sn = 0; sn < 4; ++sn) accO[sn][reg] *= al;
    }
    // O += P V  (P rows are wave-private; compiler inserts lgkm waits)
#pragma unroll
    for (int ss = 0; ss < 2; ++ss) {
      short8 pa = *(const short8*)&Ps[(w16 + l15) * 72 + ss * 32 + quad * 8];
#pragma unroll
      for (int sn = 0; sn < 4; ++sn) {
        short8 vb =
            *(const short8*)&VT[cur][(sn * 16 + l15) * 72 + ss * 32 + quad * 8];
        accO[sn] = MFMA_B16(pa, vb, accO[sn]);
      }
    }
    // write prefetched tile into the other buffer; one barrier per tile
    if (kt + 1 < ktn) {
      int nx = cur ^ 1;
      *(ushort8*)&Ks[nx][r * 72 + seg] = rk0;
      *(ushort8*)&Ks[nx][r * 72 + seg + 8] = rk1;
      *(ushort8*)&VT[nx][r * 72 + seg] = rv0;
      *(ushort8*)&VT[nx][r * 72 + seg + 8] = rv1;
      __syncthreads();
      cur = nx;
    }
  }
  // write normalized partial O (bf16) + (m, l)
  size_t pbase = (((size_t)(s * 2 + b) * 8 + h) * 1088 + qt * 64);
#pragma unroll
  for (int reg = 0; reg < 4; ++reg) {
    float inv = 1.f / li[reg];
    int rr = w16 + quad * 4 + reg;
#pragma unroll
    for (int sn = 0; sn < 4; ++sn) {
      opart[(pbase + rr) * 64 + sn * 16 + l15] = f2b(accO[sn][reg] * inv);
    }
    if (l15 == 0) {
      ml[(pbase + rr) * 2] = mi[reg];
      ml[(pbase + rr) * 2 + 1] = li[reg];
    }
  }
}

// ---------------------------------------------------------------------------
// amerge: merge the two KV-split partials -> o (bf16, in-place over q16).
// grid = 1088 x 256; one thread per (b, h, row, 4-dim group).
// ---------------------------------------------------------------------------
__global__ __launch_bounds__(256) void amerge_k(const u16* __restrict__ opart,
                                                const float* __restrict__ ml,
                                                u16* __restrict__ o) {
  int idx = blockIdx.x * 256 + threadIdx.x;  // 2*8*1088*16 = 278528
  int d4 = (idx & 15) * 4;
  int rem = idx >> 4;
  int row = rem % 1088;
  int bh = rem / 1088;
  int h = bh & 7, b = bh >> 3;
  size_t r0 = ((size_t)(0 + b) * 8 + h) * 1088 + row;  // split 0
  size_t r1 = ((size_t)(2 + b) * 8 + h) * 1088 + row;  // split 1
  float m0 = ml[r0 * 2], l0 = ml[r0 * 2 + 1];
  float m1 = ml[r1 * 2], l1 = ml[r1 * 2 + 1];
  float m = fmaxf(m0, m1);
  float w0 = l0 * __expf(m0 - m), w1 = l1 * __expf(m1 - m);
  float inv = 1.f / (w0 + w1);
  w0 *= inv;
  w1 *= inv;
  ushort4 a = *(const ushort4*)&opart[r0 * 64 + d4];
  ushort4 c = *(const ushort4*)&opart[r1 * 64 + d4];
  ushort4 ov;
  ov.x = f2b(w0 * b2f(a.x) + w1 * b2f(c.x));
  ov.y = f2b(w0 * b2f(a.y) + w1 * b2f(c.y));
  ov.z = f2b(w0 * b2f(a.z) + w1 * b2f(c.z));
  ov.w = f2b(w0 * b2f(a.w) + w1 * b2f(c.w));
  *(ushort4*)&o[(size_t)(b * 1088 + row) * 512 + h * 64 + d4] = ov;
}

// ---------------------------------------------------------------------------
// Output head matvec: out[b*1024+t] = g16[b*1088+t][0:1024].w2 + b2, fp32.
// ---------------------------------------------------------------------------
__global__ __launch_bounds__(256) void outvec_k(const u16* __restrict__ G,
                                               const float* __restrict__ w,
                                               const float* __restrict__ b2,
                                               float* __restrict__ out) {
  int row = blockIdx.x;  // 0..2047
  int b = row >> 10, tt = row & 1023;
  const u16* g = G + (size_t)(b * 1088 + tt) * 1024;
  int k0 = threadIdx.x * 4;
  ushort4 gv = *(const ushort4*)&g[k0];
  float acc = b2f(gv.x) * w[k0] + b2f(gv.y) * w[k0 + 1] +
              b2f(gv.z) * w[k0 + 2] + b2f(gv.w) * w[k0 + 3];
#pragma unroll
  for (int off = 1; off < 64; off <<= 1) acc += __shfl_xor(acc, off);
  __shared__ float part[4];
  int wv = threadIdx.x >> 6, lane = threadIdx.x & 63;
  if (lane == 0) part[wv] = acc;
  __syncthreads();
  if (threadIdx.x == 0) {
    out[row] = part[0] + part[1] + part[2] + part[3] + b2[0];
  }
}

// ---------------------------------------------------------------------------
extern "C" void kernel_launch(void* const* d_in, const int* in_sizes, int n_in,
                              void* d_out, int out_size, void* d_ws,
                              size_t ws_size, hipStream_t stream) {
  (void)in_sizes;
  (void)n_in;
  (void)out_size;
  const float* x = (const float*)d_in[0];
  const float* timesteps = (const float*)d_in[1];
  const float* cond = (const float*)d_in[2];
  const float* conv_w1 = (const float*)d_in[3];
  const float* conv_b1 = (const float*)d_in[4];
  const float* conv_w2 = (const float*)d_in[5];
  const float* conv_b2 = (const float*)d_in[6];
  const float* tpe_w1 = (const float*)d_in[7];
  const float* tpe_b1 = (const float*)d_in[8];
  const float* tpe_w2 = (const float*)d_in[9];
  const float* tpe_b2 = (const float*)d_in[10];
  const float* ln1_g = (const float*)d_in[11];
  const float* ln1_b = (const float*)d_in[12];
  const float* wq = (const float*)d_in[13];
  const float* wkv = (const float*)d_in[14];
  const float* wo = (const float*)d_in[15];
  const float* bo = (const float*)d_in[16];
  const float* ln2_g = (const float*)d_in[17];
  const float* ln2_b = (const float*)d_in[18];
  const float* ffn_w1 = (const float*)d_in[19];
  const float* ffn_b1 = (const float*)d_in[20];
  const float* ffn_w2 = (const float*)d_in[21];
  const float* ffn_b2 = (const float*)d_in[22];
  const float* tm_w1 = (const float*)d_in[23];
  const float* tm_b1 = (const float*)d_in[24];
  const float* tm_w2 = (const float*)d_in[25];
  const float* tm_b2 = (const float*)d_in[26];
  const float* fn_g = (const float*)d_in[27];
  const float* fn_b = (const float*)d_in[28];
  const float* out_w1 = (const float*)d_in[29];
  const float* out_b1 = (const float*)d_in[30];
  const float* out_w2 = (const float*)d_in[31];
  const float* out_b2 = (const float*)d_in[32];

  // Workspace layout (float offsets). Base total 6,070,272 fl = 24.3 MB.
  float* w = (float*)d_ws;
  float* te = w + 0;
  float* tpe_mid = w + 1024;
  float* time_emb = w + 5120;
  float* tm_mid = w + 6144;
  float* tm = w + 55296;                    // ends 67584
  float* hbuf = w + 131072;                 // 2176x512 fp32, ends 1245184
  u16* q16 = (u16*)(w + 1245184);           // 2176x512 bf16 (557056 fl)
  float* buf1 = w + 1245184;                // conv stage alias (524288 fl)
  u16* hb16 = (u16*)(w + 1802240);          // 2176x512 bf16
  u16* k16 = (u16*)(w + 2359296);           // 2176x64 bf16 (69632 fl)
  u16* vT16 = (u16*)(w + 2428928);          // 64x2176 bf16 (69632 fl)
  u16* mid16 = (u16*)(w + 2498560);         // 2176x2048 bf16 (2228224 fl)
  u16* im16 = mid16;                        // 2048x1792 bf16 (stem alias)
  u16* g16 = mid16;                         // 2176x1024 bf16 (head alias)
  u16* wbuf = (u16*)(w + 4726784);          // 2686976 u16, ends 6070272
  u16* wq16 = wbuf;
  u16* wkv16 = wbuf + 262144;
  u16* wo16 = wbuf + 327680;
  u16* w116 = wbuf + 589824;
  u16* w216 = wbuf + 1638400;
  u16* cw216 = wbuf;    // conv_w2 bf16 (917504), stem alias
  u16* ow116 = wbuf;    // out_w1^T bf16 (524288), head alias
  // split-K / split-KV scratch (all stream-ordered aliases of pmid/mid16):
  float* pmlp = hbuf;
  float* pmid = w + 2498560;
  u16* opart16 = (u16*)(w + 2498560);       // 2*2*8*1088*64 u16 = 1114112 fl
  float* aml = w + 2498560 + 1114112;       // 2*2*8*1088*2 fl = 69632 fl
  int big = ws_size >= (size_t)(6070272 + 2228224) * 4 ? 1 : 0;
  float* part2 = w + 6070272;

  // time embedding + time-MLP pipeline (split-K, two-phase)
  te_k<<<1, 512, 0, stream>>>(timesteps, te);
  mlpA_k<<<dim3(32, 4, 1), 256, 0, stream>>>(te, tpe_w1, pmlp, 512, 2048, 0, 0);
  mlpB_k<<<16, 256, 0, stream>>>(pmlp, tpe_b1, tpe_mid, 2048, 11, 4, 1, 0, 0);
  mlpA_k<<<dim3(8, 16, 1), 256, 0, stream>>>(tpe_mid, tpe_w2, pmlp, 2048, 512,
                                             0, 0);
  mlpB_k<<<4, 256, 0, stream>>>(pmlp, tpe_b2, time_emb, 512, 9, 16, 0, 0, 0);
  mlpA_k<<<dim3(32, 4, 12), 256, 0, stream>>>(time_emb, tm_w1, pmlp, 512, 2048,
                                              0, 512L * 2048);
  mlpB_k<<<192, 256, 0, stream>>>(pmlp, tm_b1, tm_mid, 2048, 11, 4, 1, 2048,
                                  2L * 2048);
  mlpA_k<<<dim3(8, 16, 12), 256, 0, stream>>>(tm_mid, tm_w2, pmlp, 2048, 512,
                                              2L * 2048, 2048L * 512);
  mlpB_k<<<48, 256, 0, stream>>>(pmlp, tm_b2, tm, 512, 9, 16, 0, 512,
                                 2L * 512);

  // conv stem: conv1 (fp32) -> im2col -> bf16 GEMM (conv2 + relu) -> hbuf
  conv1_k<<<2048, 256, 0, stream>>>(x, conv_w1, conv_b1, buf1);
  fcvt_k<<<896, 256, 0, stream>>>(conv_w2, cw216, 917504);
  im2col_k<<<14336, 256, 0, stream>>>(buf1, im16);
  bgemm2_k<<<dim3(8, 32, 1), 256, 0, stream>>>(
      im16, cw216, conv_b2, nullptr, nullptr, hbuf, nullptr, nullptr, nullptr,
      1792, 512, 1792, 0, MODE_BIAS | MODE_RELU | MODE_CONVROW);
  cond_k<<<256, 256, 0, stream>>>(cond, hbuf);

  for (int l = 0; l < 12; ++l) {
    wcvt5_k<<<656, 256, 0, stream>>>(
        wq + (size_t)l * 512 * 512, wkv + (size_t)l * 512 * 128,
        wo + (size_t)l * 512 * 512, ffn_w1 + (size_t)l * 512 * 2048,
        ffn_w2 + (size_t)l * 2048 * 512, wq16, wkv16, wo16, w116, w216);
    ln_k<<<2176, 256, 0, stream>>>(hbuf, hb16, ln1_g + l * 512,
                                   ln1_b + l * 512);
    // q = hb16 @ wq^T (split-K 2)
    bgemm2_k<<<dim3(8, 34, 2), 256, 0, stream>>>(
        hb16, wq16, nullptr, nullptr, nullptr, nullptr, nullptr, nullptr,
        pmid, 512, 512, 256, 1114112, 0);
    bred_k<<<1088, 256, 0, stream>>>(pmid, nullptr, nullptr, nullptr, nullptr,
                                     q16, nullptr, 1114112, 511, 9, 2,
                                     MODE_OUT16);
    // kv = hb16 @ wkv^T (split-K 2)
    bgemm2_k<<<dim3(2, 34, 2), 256, 0, stream>>>(
        hb16, wkv16, nullptr, nullptr, nullptr, nullptr, nullptr, nullptr,
        pmid, 512, 128, 256, 278528, 0);
    bred_k<<<272, 256, 0, stream>>>(pmid, nullptr, nullptr, nullptr, nullptr,
                                    k16, vT16, 278528, 127, 7, 2, MODE_KVT);
    // attention: KV-split S=2, then merge (partials alias pmid region)
    attn2_k<<<dim3(17, 8, 4), 256, 0, stream>>>(q16, k16, vT16, opart16, aml);
    amerge_k<<<1088, 256, 0, stream>>>(opart16, aml, q16);
    // o = attn @ wo^T + bo + tm + res (split-K 2)
    bgemm2_k<<<dim3(8, 34, 2), 256, 0, stream>>>(
        q16, wo16, nullptr, nullptr, nullptr, nullptr, nullptr, nullptr, pmid,
        512, 512, 256, 1114112, 0);
    bred_k<<<1088, 256, 0, stream>>>(pmid, bo + l * 512, tm + l * 1024, hbuf,
                                     hbuf, nullptr, nullptr, 1114112, 511, 9,
                                     2, MODE_BIAS | MODE_TM | MODE_RES);
    ln_k<<<2176, 256, 0, stream>>>(hbuf, hb16, ln2_g + l * 512,
                                   ln2_b + l * 512);
    // ffn1: N=2048 -> 1088 blocks, no split
    bgemm2_k<<<dim3(32, 34, 1), 256, 0, stream>>>(
        hb16, w116, ffn_b1 + l * 2048, nullptr, nullptr, nullptr, mid16,
        nullptr, nullptr, 512, 2048, 512, 0,
        MODE_BIAS | MODE_GELU | MODE_OUT16);
    // ffn2: K=2048; split-K 2 if workspace allows, else direct
    if (big) {
      bgemm2_k<<<dim3(8, 34, 2), 256, 0, stream>>>(
          mid16, w216, nullptr, nullptr, nullptr, nullptr, nullptr, nullptr,
          part2, 2048, 512, 1024, 1114112, 0);
      bred_k<<<1088, 256, 0, stream>>>(part2, ffn_b2 + l * 512, nullptr, hbuf,
                                       hbuf, nullptr, nullptr, 1114112, 511, 9,
                                       2, MODE_BIAS | MODE_RES);
    } else {
      bgemm2_k<<<dim3(8, 34, 1), 256, 0, stream>>>(
          mid16, w216, ffn_b2 + l * 512, nullptr, hbuf, hbuf, nullptr,
          nullptr, nullptr, 2048, 512, 2048, 0, MODE_BIAS | MODE_RES);
    }
  }
  ln_k<<<2176, 256, 0, stream>>>(hbuf, hb16, fn_g, fn_b);
  wcvtT_k<<<128, 256, 0, stream>>>(out_w1, ow116, 512, 1024);
  bgemm2_k<<<dim3(16, 34, 1), 256, 0, stream>>>(
      hb16, ow116, out_b1, nullptr, nullptr, nullptr, g16, nullptr, nullptr,
      512, 1024, 512, 0, MODE_BIAS | MODE_GELU | MODE_OUT16);
  outvec_k<<<2048, 256, 0, stream>>>(g16, out_w2, out_b2, (float*)d_out);
}

// Round 8
// 1645.948 us; speedup vs baseline: 2.0933x; 1.1303x over previous
//
#include <hip/hip_runtime.h>
#include <hip/hip_bf16.h>
#include <math.h>

// ---------------------------------------------------------------------------
// MusicDiffusionTransformer forward, MI355X (gfx950).
// Round 9 (third resubmit; three benches lost to GPU acquisition timeouts):
// big-workspace layout (~256 MiB available per fillBuffer evidence).
//  - attn2: KV-split S=4 (1088 blocks; serial tile loop 17 -> 4/5)
//  - fused q+kv GEMM (N=640, contiguous weights) + 3-way bred epilogue
//  - bredln_k: split-K reduce + epilogue + LayerNorm fused (kills ln_k x24)
//  - wcvt5b_k: all 12 layers' weights converted in ONE launch into an arena
// Fallback to round-8 sequence when ws_size < 120 MB.
// ---------------------------------------------------------------------------

typedef unsigned short u16;
typedef __attribute__((ext_vector_type(8))) short short8;
typedef __attribute__((ext_vector_type(8))) unsigned short ushort8;
typedef __attribute__((ext_vector_type(4))) float f32x4;

#define MFMA_B16(a, b, c) __builtin_amdgcn_mfma_f32_16x16x32_bf16(a, b, c, 0, 0, 0)

__device__ __forceinline__ float gelu_f(float x) {
  return 0.5f * x * (1.f + erff(x * 0.70710678118654752f));
}
__device__ __forceinline__ u16 f2b(float x) {
  union { float f; unsigned u; } v;
  v.f = x;
  unsigned r = (v.u + 0x7FFF + ((v.u >> 16) & 1)) >> 16;
  return (u16)r;
}
__device__ __forceinline__ float b2f(u16 u) {
  union { unsigned u; float f; } v;
  v.u = ((unsigned)u) << 16;
  return v.f;
}

#define MODE_BIAS 1
#define MODE_GELU 2
#define MODE_RES 4
#define MODE_TM 8
#define MODE_OUT16 16
#define MODE_KVT 32
#define MODE_RELU 64
#define MODE_CONVROW 128
#define MODE_QKV 256

// ---------------------------------------------------------------------------
// te: sinusoidal time embedding (2 x 512)
// ---------------------------------------------------------------------------
__global__ void te_k(const float* __restrict__ ts, float* __restrict__ te) {
  int t = threadIdx.x;
  int b = t >> 8, i = t & 255;
  float tv = ts[b];
  float fr = __expf((float)i * (-9.210340371976184f / 255.f));
  float arg = tv * fr;
  te[b * 512 + i] = sinf(arg);
  te[b * 512 + 256 + i] = cosf(arg);
}

// ---------------------------------------------------------------------------
// Split-K M=2 MLP, phase A.
// ---------------------------------------------------------------------------
__global__ __launch_bounds__(256) void mlpA_k(const float* __restrict__ A,
                                              const float* __restrict__ B,
                                              float* __restrict__ part, int K,
                                              int N, long sA, long sB) {
  int l = blockIdx.z;
  const float* Ap = A + (size_t)l * sA;
  const float* Bp = B + (size_t)l * sB;
  int KS = K >> 7;
  int tid = threadIdx.x;
  int c16 = tid & 15;
  int col = blockIdx.x * 64 + c16 * 4;
  int kr = tid >> 4;
  int k0 = blockIdx.y * 128 + kr;
  float4 a0 = {0.f, 0.f, 0.f, 0.f}, a1 = {0.f, 0.f, 0.f, 0.f};
#pragma unroll
  for (int i = 0; i < 8; ++i) {
    int k = k0 + i * 16;
    float4 bv = *(const float4*)&Bp[(size_t)k * N + col];
    float x0 = Ap[k], x1 = Ap[K + k];
    a0.x = fmaf(x0, bv.x, a0.x);
    a0.y = fmaf(x0, bv.y, a0.y);
    a0.z = fmaf(x0, bv.z, a0.z);
    a0.w = fmaf(x0, bv.w, a0.w);
    a1.x = fmaf(x1, bv.x, a1.x);
    a1.y = fmaf(x1, bv.y, a1.y);
    a1.z = fmaf(x1, bv.z, a1.z);
    a1.w = fmaf(x1, bv.w, a1.w);
  }
#pragma unroll
  for (int off = 16; off < 64; off <<= 1) {
    a0.x += __shfl_xor(a0.x, off);
    a0.y += __shfl_xor(a0.y, off);
    a0.z += __shfl_xor(a0.z, off);
    a0.w += __shfl_xor(a0.w, off);
    a1.x += __shfl_xor(a1.x, off);
    a1.y += __shfl_xor(a1.y, off);
    a1.z += __shfl_xor(a1.z, off);
    a1.w += __shfl_xor(a1.w, off);
  }
  __shared__ float red[4][2][64];
  int w = tid >> 6, lane = tid & 63;
  if (lane < 16) {
    *(float4*)&red[w][0][c16 * 4] = a0;
    *(float4*)&red[w][1][c16 * 4] = a1;
  }
  __syncthreads();
  if (tid < 128) {
    int m = tid >> 6, c = tid & 63;
    float s = red[0][m][c] + red[1][m][c] + red[2][m][c] + red[3][m][c];
    part[(((size_t)l * KS + blockIdx.y) * 2 + m) * N + blockIdx.x * 64 + c] = s;
  }
}

// ---------------------------------------------------------------------------
// Split-K M=2 MLP, phase B.
// ---------------------------------------------------------------------------
__global__ __launch_bounds__(256) void mlpB_k(const float* __restrict__ part,
                                              const float* __restrict__ bias,
                                              float* __restrict__ C, int N,
                                              int lgN, int KS, int dogelu,
                                              long sb, long sC) {
  int idx = blockIdx.x * 256 + threadIdx.x;
  int col = idx & (N - 1);
  int lm = idx >> lgN;
  int m = lm & 1, l = lm >> 1;
  float s = 0.f;
  for (int ks = 0; ks < KS; ++ks)
    s += part[(((size_t)l * KS + ks) * 2 + m) * N + col];
  s += bias[(size_t)l * sb + col];
  if (dogelu) s = gelu_f(s);
  C[(size_t)l * sC + (size_t)m * N + col] = s;
}

// ---------------------------------------------------------------------------
// conv1: (2,1,1024) -> (2,256,1024), k=7 pad=3, ReLU. buf1[b][co][t] fp32.
// ---------------------------------------------------------------------------
__global__ __launch_bounds__(256) void conv1_k(const float* __restrict__ x,
                                               const float* __restrict__ w1,
                                               const float* __restrict__ b1,
                                               float* __restrict__ buf1) {
  int idx = blockIdx.x * 256 + threadIdx.x;
  int t = idx & 1023, co = (idx >> 10) & 255, b = idx >> 18;
  float acc = b1[co];
#pragma unroll
  for (int k = 0; k < 7; ++k) {
    int gt = t + k - 3;
    if (gt >= 0 && gt < 1024)
      acc = fmaf(w1[co * 7 + k], x[b * 1024 + gt], acc);
  }
  buf1[idx] = fmaxf(acc, 0.f);
}

// ---------------------------------------------------------------------------
// im2col for conv2: buf1[b][ci][t] -> A16[b*1024+t][ci*7+k] bf16 (0-padded)
// ---------------------------------------------------------------------------
__global__ __launch_bounds__(256) void im2col_k(const float* __restrict__ buf1,
                                                u16* __restrict__ A16) {
  int idx = blockIdx.x * 256 + threadIdx.x;  // 2048*1792
  int c = idx % 1792;
  int m = idx / 1792;
  int b = m >> 10, tt = m & 1023;
  int ci = c / 7, k = c - ci * 7;
  int gt = tt + k - 3;
  float v = (gt >= 0 && gt < 1024) ? buf1[((b * 256) + ci) * 1024 + gt] : 0.f;
  A16[idx] = f2b(v);
}

// ---------------------------------------------------------------------------
// copy cond (fp32) into hbuf rows 1024..1087 per batch
// ---------------------------------------------------------------------------
__global__ void cond_k(const float* __restrict__ cond,
                       float* __restrict__ hbuf) {
  int idx = blockIdx.x * 256 + threadIdx.x;  // 65536
  int b = idx >> 15, rem = idx & 32767;
  int j = rem >> 9, cc = rem & 511;
  hbuf[(size_t)(b * 1088 + 1024 + j) * 512 + cc] = cond[idx];
}

// ---------------------------------------------------------------------------
// LayerNorm in-place (fp32) + bf16 copy. grid = 2176 rows.
// ---------------------------------------------------------------------------
__global__ __launch_bounds__(256) void ln_k(float* __restrict__ h,
                                            u16* __restrict__ h16,
                                            const float* __restrict__ g,
                                            const float* __restrict__ bb) {
  int row = blockIdx.x;
  float* p = h + (size_t)row * 512;
  int t = threadIdx.x;
  float x0 = p[t], x1 = p[t + 256];
  float s = x0 + x1, q = x0 * x0 + x1 * x1;
#pragma unroll
  for (int off = 1; off < 64; off <<= 1) {
    s += __shfl_xor(s, off);
    q += __shfl_xor(q, off);
  }
  __shared__ float ps[4], pq[4];
  int w = t >> 6, lane = t & 63;
  if (lane == 0) {
    ps[w] = s;
    pq[w] = q;
  }
  __syncthreads();
  s = ps[0] + ps[1] + ps[2] + ps[3];
  q = pq[0] + pq[1] + pq[2] + pq[3];
  float mean = s * (1.f / 512.f);
  float var = q * (1.f / 512.f) - mean * mean;
  float rs = rsqrtf(var + 1e-5f);
  float v0 = (x0 - mean) * rs * g[t] + bb[t];
  float v1 = (x1 - mean) * rs * g[t + 256] + bb[t + 256];
  p[t] = v0;
  p[t + 256] = v1;
  h16[(size_t)row * 512 + t] = f2b(v0);
  h16[(size_t)row * 512 + t + 256] = f2b(v1);
}

// ---------------------------------------------------------------------------
// Weight convert+transpose tile: src fp32 [K][N] -> dst bf16 [N][K], 64x64.
// ---------------------------------------------------------------------------
__device__ __forceinline__ void wcvt_tile(float (*T)[65],
                                          const float* __restrict__ src,
                                          u16* __restrict__ dst, int K, int N,
                                          int tk, int tn, int t) {
  int kl = t >> 2, nseg = (t & 3) * 16;
#pragma unroll
  for (int j = 0; j < 4; ++j) {
    float4 v =
        *(const float4*)&src[(size_t)(tk * 64 + kl) * N + tn * 64 + nseg + j * 4];
    T[nseg + j * 4 + 0][kl] = v.x;
    T[nseg + j * 4 + 1][kl] = v.y;
    T[nseg + j * 4 + 2][kl] = v.z;
    T[nseg + j * 4 + 3][kl] = v.w;
  }
  __syncthreads();
  int nl = t >> 2, kseg = (t & 3) * 16;
#pragma unroll
  for (int j = 0; j < 4; ++j) {
    ushort4 o;
    o.x = f2b(T[nl][kseg + j * 4 + 0]);
    o.y = f2b(T[nl][kseg + j * 4 + 1]);
    o.z = f2b(T[nl][kseg + j * 4 + 2]);
    o.w = f2b(T[nl][kseg + j * 4 + 3]);
    *(ushort4*)&dst[(size_t)(tn * 64 + nl) * K + tk * 64 + kseg + j * 4] = o;
  }
}

__device__ __forceinline__ void wcvt5_body(const float* wq, const float* wkv,
                                           const float* wo, const float* w1,
                                           const float* w2, u16* dq, u16* dkv,
                                           u16* dwo, u16* d1, u16* d2,
                                           float (*T)[65], int bid, int t) {
  if (bid < 64) {
    wcvt_tile(T, wq, dq, 512, 512, bid >> 3, bid & 7, t);
  } else if (bid < 80) {
    int id = bid - 64;
    wcvt_tile(T, wkv, dkv, 512, 128, id >> 1, id & 1, t);
  } else if (bid < 144) {
    int id = bid - 80;
    wcvt_tile(T, wo, dwo, 512, 512, id >> 3, id & 7, t);
  } else if (bid < 400) {
    int id = bid - 144;
    wcvt_tile(T, w1, d1, 512, 2048, id >> 5, id & 31, t);
  } else {
    int id = bid - 400;
    wcvt_tile(T, w2, d2, 2048, 512, id >> 3, id & 7, t);
  }
}

// Per-layer (fallback). grid = 656 tiles.
__global__ __launch_bounds__(256) void wcvt5_k(
    const float* wq, const float* wkv, const float* wo, const float* w1,
    const float* w2, u16* dq, u16* dkv, u16* dwo, u16* d1, u16* d2) {
  __shared__ float T[64][65];
  wcvt5_body(wq, wkv, wo, w1, w2, dq, dkv, dwo, d1, d2, T, blockIdx.x,
             threadIdx.x);
}

// Batched: all 12 layers into arena (stride 2686976 u16). grid = (656, 12).
__global__ __launch_bounds__(256) void wcvt5b_k(
    const float* wq, const float* wkv, const float* wo, const float* w1,
    const float* w2, u16* wall) {
  __shared__ float T[64][65];
  int l = blockIdx.y;
  u16* d = wall + (size_t)l * 2686976;
  wcvt5_body(wq + (size_t)l * 262144, wkv + (size_t)l * 65536,
             wo + (size_t)l * 262144, w1 + (size_t)l * 1048576,
             w2 + (size_t)l * 1048576, d, d + 262144, d + 327680, d + 589824,
             d + 1638400, T, blockIdx.x, threadIdx.x);
}

// Generic single matrix transpose-convert (for out_w1: 512x1024).
__global__ __launch_bounds__(256) void wcvtT_k(const float* src, u16* dst,
                                               int K, int N) {
  __shared__ float T[64][65];
  int nt = N >> 6;
  int tk = blockIdx.x / nt, tn = blockIdx.x % nt;
  wcvt_tile(T, src, dst, K, N, tk, tn, threadIdx.x);
}

// Flat fp32 -> bf16 cast (conv_w2: already [co][ci*7+k] = [N][K]).
__global__ __launch_bounds__(256) void fcvt_k(const float* __restrict__ src,
                                              u16* __restrict__ dst, int n) {
  int i = (blockIdx.x * 256 + threadIdx.x) * 4;
  if (i >= n) return;
  float4 v = *(const float4*)&src[i];
  ushort4 o;
  o.x = f2b(v.x);
  o.y = f2b(v.y);
  o.z = f2b(v.z);
  o.w = f2b(v.w);
  *(ushort4*)&dst[i] = o;
}

// ---------------------------------------------------------------------------
// bgemm2: C(MxN) = A(MxK bf16 rm) @ B^T(NxK bf16 rm), 64x64 tile, BK=64,
// 4 waves (2x2) of 32x32. Double-buffered LDS (stride 72), prefetch-to-reg,
// ONE barrier per K-step. grid = (N/64, M/64, S).
// S>1: write fp32 partial [kz][M][N] (no epilogue), reduce in bred/bredln.
// ---------------------------------------------------------------------------
__global__ __launch_bounds__(256) void bgemm2_k(
    const u16* __restrict__ A, const u16* __restrict__ B,
    const float* __restrict__ bias, const float* __restrict__ tmv,
    const float* __restrict__ res, float* __restrict__ Cf,
    u16* __restrict__ C16, u16* __restrict__ C16b, float* __restrict__ part,
    int K, int N, int Kblk, int MN, int mode) {
  __shared__ u16 As[2][64 * 72];
  __shared__ u16 Bs[2][64 * 72];
  int t = threadIdx.x;
  int n0 = blockIdx.x * 64, m0 = blockIdx.y * 64;
  int kz = blockIdx.z;
  int wid = t >> 6, lane = t & 63;
  int quad = lane >> 4, l15 = lane & 15;
  int wr = (wid >> 1) * 32, wc = (wid & 1) * 32;
  int sr = t >> 2, sc = (t & 3) * 16;
  const u16* Ap = A + (size_t)(m0 + sr) * K + (size_t)kz * Kblk + sc;
  const u16* Bp = B + (size_t)(n0 + sr) * K + (size_t)kz * Kblk + sc;

  f32x4 acc[2][2];
#pragma unroll
  for (int i = 0; i < 2; ++i)
#pragma unroll
    for (int j = 0; j < 2; ++j) acc[i][j] = (f32x4){0.f, 0.f, 0.f, 0.f};

  int nt = Kblk >> 6;
  ushort8 ra0 = *(const ushort8*)Ap;
  ushort8 ra1 = *(const ushort8*)(Ap + 8);
  ushort8 rb0 = *(const ushort8*)Bp;
  ushort8 rb1 = *(const ushort8*)(Bp + 8);
  *(ushort8*)&As[0][sr * 72 + sc] = ra0;
  *(ushort8*)&As[0][sr * 72 + sc + 8] = ra1;
  *(ushort8*)&Bs[0][sr * 72 + sc] = rb0;
  *(ushort8*)&Bs[0][sr * 72 + sc + 8] = rb1;
  __syncthreads();
  int cur = 0;
  for (int tt = 0; tt < nt; ++tt) {
    if (tt + 1 < nt) {
      const u16* ap = Ap + (tt + 1) * 64;
      const u16* bp = Bp + (tt + 1) * 64;
      ra0 = *(const ushort8*)ap;
      ra1 = *(const ushort8*)(ap + 8);
      rb0 = *(const ushort8*)bp;
      rb1 = *(const ushort8*)(bp + 8);
    }
    short8 af[2][2], bf[2][2];
#pragma unroll
    for (int s = 0; s < 2; ++s)
#pragma unroll
      for (int i = 0; i < 2; ++i) {
        af[i][s] =
            *(const short8*)&As[cur][(wr + i * 16 + l15) * 72 + s * 32 + quad * 8];
        bf[i][s] =
            *(const short8*)&Bs[cur][(wc + i * 16 + l15) * 72 + s * 32 + quad * 8];
      }
#pragma unroll
    for (int s = 0; s < 2; ++s)
#pragma unroll
      for (int i = 0; i < 2; ++i)
#pragma unroll
        for (int j = 0; j < 2; ++j)
          acc[i][j] = MFMA_B16(af[i][s], bf[j][s], acc[i][j]);
    if (tt + 1 < nt) {
      int nx = cur ^ 1;
      *(ushort8*)&As[nx][sr * 72 + sc] = ra0;
      *(ushort8*)&As[nx][sr * 72 + sc + 8] = ra1;
      *(ushort8*)&Bs[nx][sr * 72 + sc] = rb0;
      *(ushort8*)&Bs[nx][sr * 72 + sc + 8] = rb1;
      __syncthreads();
      cur = nx;
    }
  }

  if (gridDim.z > 1) {
#pragma unroll
    for (int i = 0; i < 2; ++i)
#pragma unroll
      for (int reg = 0; reg < 4; ++reg) {
        int row = m0 + wr + i * 16 + quad * 4 + reg;
#pragma unroll
        for (int j = 0; j < 2; ++j) {
          int col = n0 + wc + j * 16 + l15;
          part[(size_t)kz * MN + (size_t)row * N + col] = acc[i][j][reg];
        }
      }
    return;
  }

#pragma unroll
  for (int i = 0; i < 2; ++i) {
#pragma unroll
    for (int reg = 0; reg < 4; ++reg) {
      int row = m0 + wr + i * 16 + quad * 4 + reg;
      int orow = (mode & MODE_CONVROW) ? row + ((row >> 10) << 6) : row;
#pragma unroll
      for (int j = 0; j < 2; ++j) {
        int col = n0 + wc + j * 16 + l15;
        float v = acc[i][j][reg];
        if (mode & MODE_BIAS) v += bias[col];
        if (mode & MODE_TM) v += tmv[(row >= 1088 ? 512 : 0) + col];
        if (mode & MODE_RES) v += res[(size_t)orow * 512 + col];
        if (mode & MODE_GELU) v = gelu_f(v);
        if (mode & MODE_RELU) v = fmaxf(v, 0.f);
        if (mode & MODE_KVT) {
          if (col < 64)
            C16[orow * 64 + col] = f2b(v);
          else
            C16b[(size_t)(col - 64) * 2176 + orow] = f2b(v);
        } else if (mode & MODE_OUT16) {
          C16[(size_t)orow * N + col] = f2b(v);
        } else {
          Cf[(size_t)orow * N + col] = v;
        }
      }
    }
  }
}

// ---------------------------------------------------------------------------
// bred: reduce S split-K fp32 partials + fused epilogue. Any N % 4 == 0.
// MODE_QKV: N=640 -> col<512: q (C16), 512..575: k (C16b), >=576: vT (C16c).
// ---------------------------------------------------------------------------
__global__ __launch_bounds__(256) void bred_k(
    const float* __restrict__ part, const float* __restrict__ bias,
    const float* __restrict__ tmv, const float* __restrict__ res,
    float* __restrict__ Cf, u16* __restrict__ C16, u16* __restrict__ C16b,
    u16* __restrict__ C16c, int MN, int N, int S, int mode) {
  int idx = (blockIdx.x * 256 + threadIdx.x) * 4;
  if (idx >= MN) return;
  int row = idx / N;
  int col = idx - row * N;
  float4 s = *(const float4*)&part[idx];
  for (int ss = 1; ss < S; ++ss) {
    float4 p = *(const float4*)&part[(size_t)ss * MN + idx];
    s.x += p.x;
    s.y += p.y;
    s.z += p.z;
    s.w += p.w;
  }
  float v[4] = {s.x, s.y, s.z, s.w};
#pragma unroll
  for (int j = 0; j < 4; ++j) {
    float vv = v[j];
    int c = col + j;
    if (mode & MODE_BIAS) vv += bias[c];
    if (mode & MODE_TM) vv += tmv[(row >= 1088 ? 512 : 0) + c];
    if (mode & MODE_RES) vv += res[(size_t)row * 512 + c];
    if (mode & MODE_GELU) vv = gelu_f(vv);
    v[j] = vv;
  }
  if (mode & MODE_QKV) {
    if (col < 512) {
      ushort4 o;
      o.x = f2b(v[0]);
      o.y = f2b(v[1]);
      o.z = f2b(v[2]);
      o.w = f2b(v[3]);
      *(ushort4*)&C16[(size_t)row * 512 + col] = o;
    } else if (col < 576) {
      ushort4 o;
      o.x = f2b(v[0]);
      o.y = f2b(v[1]);
      o.z = f2b(v[2]);
      o.w = f2b(v[3]);
      *(ushort4*)&C16b[row * 64 + (col - 512)] = o;
    } else {
#pragma unroll
      for (int j = 0; j < 4; ++j)
        C16c[(size_t)(col - 576 + j) * 2176 + row] = f2b(v[j]);
    }
  } else if (mode & MODE_KVT) {
    if (col < 64) {
      ushort4 o;
      o.x = f2b(v[0]);
      o.y = f2b(v[1]);
      o.z = f2b(v[2]);
      o.w = f2b(v[3]);
      *(ushort4*)&C16[row * 64 + col] = o;
    } else {
#pragma unroll
      for (int j = 0; j < 4; ++j)
        C16b[(size_t)(col - 64 + j) * 2176 + row] = f2b(v[j]);
    }
  } else if (mode & MODE_OUT16) {
    ushort4 o;
    o.x = f2b(v[0]);
    o.y = f2b(v[1]);
    o.z = f2b(v[2]);
    o.w = f2b(v[3]);
    *(ushort4*)&C16[idx] = o;
  } else {
    float4 o = {v[0], v[1], v[2], v[3]};
    *(float4*)&Cf[idx] = o;
  }
}

// ---------------------------------------------------------------------------
// bredln: split-K reduce + epilogue (bias/tm/res) + LayerNorm, fused.
// grid = 2176 rows x 256 threads (2 cols/thread, N=512, MN=1114112).
// Writes normalized fp32 to hbuf (residual base) + bf16 to h16.
// ---------------------------------------------------------------------------
__global__ __launch_bounds__(256) void bredln_k(
    const float* __restrict__ part, const float* __restrict__ bias,
    const float* __restrict__ tmv, float* __restrict__ hbuf,
    u16* __restrict__ h16, const float* __restrict__ g,
    const float* __restrict__ bb, int S, int mode) {
  int row = blockIdx.x;
  int t = threadIdx.x;
  size_t base = (size_t)row * 512;
  float v0 = part[base + t], v1 = part[base + t + 256];
  for (int ss = 1; ss < S; ++ss) {
    v0 += part[(size_t)ss * 1114112 + base + t];
    v1 += part[(size_t)ss * 1114112 + base + t + 256];
  }
  if (mode & MODE_BIAS) {
    v0 += bias[t];
    v1 += bias[t + 256];
  }
  if (mode & MODE_TM) {
    int off = (row >= 1088) ? 512 : 0;
    v0 += tmv[off + t];
    v1 += tmv[off + t + 256];
  }
  if (mode & MODE_RES) {
    v0 += hbuf[base + t];
    v1 += hbuf[base + t + 256];
  }
  float s = v0 + v1, q = v0 * v0 + v1 * v1;
#pragma unroll
  for (int off = 1; off < 64; off <<= 1) {
    s += __shfl_xor(s, off);
    q += __shfl_xor(q, off);
  }
  __shared__ float ps[4], pq[4];
  int w = t >> 6, lane = t & 63;
  if (lane == 0) {
    ps[w] = s;
    pq[w] = q;
  }
  __syncthreads();
  s = ps[0] + ps[1] + ps[2] + ps[3];
  q = pq[0] + pq[1] + pq[2] + pq[3];
  float mean = s * (1.f / 512.f);
  float var = q * (1.f / 512.f) - mean * mean;
  float rs = rsqrtf(var + 1e-5f);
  float n0 = (v0 - mean) * rs * g[t] + bb[t];
  float n1 = (v1 - mean) * rs * g[t + 256] + bb[t + 256];
  hbuf[base + t] = n0;
  hbuf[base + t + 256] = n1;
  h16[base + t] = f2b(n0);
  h16[base + t + 256] = f2b(n1);
}

// ---------------------------------------------------------------------------
// attn2: MFMA flash attention with KV-split (nsplit) + double-buffered K/V
// staging. grid = (17 qt, 8 h, 2b x nsplit). Split s covers a contiguous
// range of the 17 KV tiles. Writes normalized partial O (bf16) + (m, l).
// ---------------------------------------------------------------------------
__global__ __launch_bounds__(256) void attn2_k(const u16* __restrict__ q,
                                               const u16* __restrict__ k16,
                                               const u16* __restrict__ vT16,
                                               u16* __restrict__ opart,
                                               float* __restrict__ ml,
                                               int nsplit) {
  __shared__ u16 Qs[64 * 72];
  __shared__ u16 Ks[2][64 * 72];
  __shared__ u16 VT[2][64 * 72];
  __shared__ u16 Ps[64 * 72];
  int t = threadIdx.x;
  int qt = blockIdx.x, h = blockIdx.y;
  int zz = blockIdx.z;
  int s = zz % nsplit, b = zz / nsplit;
  int tbase = 17 / nsplit, trem = 17 % nsplit;
  int kt0 = s * tbase + (s < trem ? s : trem);
  int ktn = tbase + (s < trem ? 1 : 0);
  int wid = t >> 6, lane = t & 63;
  int quad = lane >> 4, l15 = lane & 15;
  int w16 = wid * 16;
  int r = t >> 2, seg = (t & 3) * 16;
  {
    const u16* qp = q + (size_t)(b * 1088 + qt * 64 + r) * 512 + h * 64 + seg;
    *(ushort8*)&Qs[r * 72 + seg] = *(const ushort8*)qp;
    *(ushort8*)&Qs[r * 72 + seg + 8] = *(const ushort8*)(qp + 8);
  }
  const u16* kbase = k16 + (size_t)(b * 1088 + kt0 * 64 + r) * 64 + seg;
  const u16* vbase = vT16 + (size_t)r * 2176 + b * 1088 + kt0 * 64 + seg;
  *(ushort8*)&Ks[0][r * 72 + seg] = *(const ushort8*)kbase;
  *(ushort8*)&Ks[0][r * 72 + seg + 8] = *(const ushort8*)(kbase + 8);
  *(ushort8*)&VT[0][r * 72 + seg] = *(const ushort8*)vbase;
  *(ushort8*)&VT[0][r * 72 + seg + 8] = *(const ushort8*)(vbase + 8);
  __syncthreads();

  f32x4 accO[4];
#pragma unroll
  for (int i = 0; i < 4; ++i) accO[i] = (f32x4){0.f, 0.f, 0.f, 0.f};
  float mi[4] = {-1e30f, -1e30f, -1e30f, -1e30f};
  float li[4] = {0.f, 0.f, 0.f, 0.f};

  int cur = 0;
  ushort8 rk0, rk1, rv0, rv1;
  for (int kt = 0; kt < ktn; ++kt) {
    if (kt + 1 < ktn) {
      const u16* kp = kbase + (size_t)(kt + 1) * 64 * 64;
      const u16* vp = vbase + (kt + 1) * 64;
      rk0 = *(const ushort8*)kp;
      rk1 = *(const ushort8*)(kp + 8);
      rv0 = *(const ushort8*)vp;
      rv1 = *(const ushort8*)(vp + 8);
    }
    f32x4 sc[4];
#pragma unroll
    for (int sn = 0; sn < 4; ++sn) sc[sn] = (f32x4){0.f, 0.f, 0.f, 0.f};
#pragma unroll
    for (int ss = 0; ss < 2; ++ss) {
      short8 a = *(const short8*)&Qs[(w16 + l15) * 72 + ss * 32 + quad * 8];
#pragma unroll
      for (int sn = 0; sn < 4; ++sn) {
        short8 bb =
            *(const short8*)&Ks[cur][(sn * 16 + l15) * 72 + ss * 32 + quad * 8];
        sc[sn] = MFMA_B16(a, bb, sc[sn]);
      }
    }
#pragma unroll
    for (int reg = 0; reg < 4; ++reg) {
      float s0 = sc[0][reg] * 0.125f, s1 = sc[1][reg] * 0.125f;
      float s2 = sc[2][reg] * 0.125f, s3 = sc[3][reg] * 0.125f;
      float mx = fmaxf(fmaxf(s0, s1), fmaxf(s2, s3));
#pragma unroll
      for (int off = 1; off < 16; off <<= 1) mx = fmaxf(mx, __shfl_xor(mx, off));
      float mn = fmaxf(mi[reg], mx);
      float al = __expf(mi[reg] - mn);
      mi[reg] = mn;
      float p0 = __expf(s0 - mn), p1 = __expf(s1 - mn);
      float p2 = __expf(s2 - mn), p3 = __expf(s3 - mn);
      int rr = (w16 + quad * 4 + reg) * 72 + l15;
      Ps[rr] = f2b(p0);
      Ps[rr + 16] = f2b(p1);
      Ps[rr + 32] = f2b(p2);
      Ps[rr + 48] = f2b(p3);
      float psum = p0 + p1 + p2 + p3;
#pragma unroll
      for (int off = 1; off < 16; off <<= 1) psum += __shfl_xor(psum, off);
      li[reg] = li[reg] * al + psum;
#pragma unroll
      for (int sn = 0; sn < 4; ++sn) accO[sn][reg] *= al;
    }
#pragma unroll
    for (int ss = 0; ss < 2; ++ss) {
      short8 pa = *(const short8*)&Ps[(w16 + l15) * 72 + ss * 32 + quad * 8];
#pragma unroll
      for (int sn = 0; sn < 4; ++sn) {
        short8 vb =
            *(const short8*)&VT[cur][(sn * 16 + l15) * 72 + ss * 32 + quad * 8];
        accO[sn] = MFMA_B16(pa, vb, accO[sn]);
      }
    }
    if (kt + 1 < ktn) {
      int nx = cur ^ 1;
      *(ushort8*)&Ks[nx][r * 72 + seg] = rk0;
      *(ushort8*)&Ks[nx][r * 72 + seg + 8] = rk1;
      *(ushort8*)&VT[nx][r * 72 + seg] = rv0;
      *(ushort8*)&VT[nx][r * 72 + seg + 8] = rv1;
      __syncthreads();
      cur = nx;
    }
  }
  size_t pbase = (((size_t)(s * 2 + b) * 8 + h) * 1088 + qt * 64);
#pragma unroll
  for (int reg = 0; reg < 4; ++reg) {
    float inv = 1.f / li[reg];
    int rr = w16 + quad * 4 + reg;
#pragma unroll
    for (int sn = 0; sn < 4; ++sn) {
      opart[(pbase + rr) * 64 + sn * 16 + l15] = f2b(accO[sn][reg] * inv);
    }
    if (l15 == 0) {
      ml[(pbase + rr) * 2] = mi[reg];
      ml[(pbase + rr) * 2 + 1] = li[reg];
    }
  }
}

// ---------------------------------------------------------------------------
// amerge: merge S KV-split partials -> o (bf16, in-place over q16).
// grid = 1088 x 256; one thread per (b, h, row, 4-dim group).
// ---------------------------------------------------------------------------
__global__ __launch_bounds__(256) void amerge_k(const u16* __restrict__ opart,
                                                const float* __restrict__ ml,
                                                u16* __restrict__ o, int S) {
  int idx = blockIdx.x * 256 + threadIdx.x;  // 2*8*1088*16 = 278528
  int d4 = (idx & 15) * 4;
  int rem = idx >> 4;
  int row = rem % 1088;
  int bh = rem / 1088;
  int h = bh & 7, b = bh >> 3;
  float m = -1e30f;
  for (int s = 0; s < S; ++s) {
    size_t rs = ((size_t)(s * 2 + b) * 8 + h) * 1088 + row;
    m = fmaxf(m, ml[rs * 2]);
  }
  float a0 = 0.f, a1 = 0.f, a2 = 0.f, a3 = 0.f, wsum = 0.f;
  for (int s = 0; s < S; ++s) {
    size_t rs = ((size_t)(s * 2 + b) * 8 + h) * 1088 + row;
    float wgt = ml[rs * 2 + 1] * __expf(ml[rs * 2] - m);
    wsum += wgt;
    ushort4 a = *(const ushort4*)&opart[rs * 64 + d4];
    a0 += wgt * b2f(a.x);
    a1 += wgt * b2f(a.y);
    a2 += wgt * b2f(a.z);
    a3 += wgt * b2f(a.w);
  }
  float inv = 1.f / wsum;
  ushort4 ov;
  ov.x = f2b(a0 * inv);
  ov.y = f2b(a1 * inv);
  ov.z = f2b(a2 * inv);
  ov.w = f2b(a3 * inv);
  *(ushort4*)&o[(size_t)(b * 1088 + row) * 512 + h * 64 + d4] = ov;
}

// ---------------------------------------------------------------------------
// Output head matvec: out[b*1024+t] = g16[b*1088+t][0:1024].w2 + b2, fp32.
// ---------------------------------------------------------------------------
__global__ __launch_bounds__(256) void outvec_k(const u16* __restrict__ G,
                                               const float* __restrict__ w,
                                               const float* __restrict__ b2,
                                               float* __restrict__ out) {
  int row = blockIdx.x;  // 0..2047
  int b = row >> 10, tt = row & 1023;
  const u16* g = G + (size_t)(b * 1088 + tt) * 1024;
  int k0 = threadIdx.x * 4;
  ushort4 gv = *(const ushort4*)&g[k0];
  float acc = b2f(gv.x) * w[k0] + b2f(gv.y) * w[k0 + 1] +
              b2f(gv.z) * w[k0 + 2] + b2f(gv.w) * w[k0 + 3];
#pragma unroll
  for (int off = 1; off < 64; off <<= 1) acc += __shfl_xor(acc, off);
  __shared__ float part[4];
  int wv = threadIdx.x >> 6, lane = threadIdx.x & 63;
  if (lane == 0) part[wv] = acc;
  __syncthreads();
  if (threadIdx.x == 0) {
    out[row] = part[0] + part[1] + part[2] + part[3] + b2[0];
  }
}

// ---------------------------------------------------------------------------
extern "C" void kernel_launch(void* const* d_in, const int* in_sizes, int n_in,
                              void* d_out, int out_size, void* d_ws,
                              size_t ws_size, hipStream_t stream) {
  (void)in_sizes;
  (void)n_in;
  (void)out_size;
  const float* x = (const float*)d_in[0];
  const float* timesteps = (const float*)d_in[1];
  const float* cond = (const float*)d_in[2];
  const float* conv_w1 = (const float*)d_in[3];
  const float* conv_b1 = (const float*)d_in[4];
  const float* conv_w2 = (const float*)d_in[5];
  const float* conv_b2 = (const float*)d_in[6];
  const float* tpe_w1 = (const float*)d_in[7];
  const float* tpe_b1 = (const float*)d_in[8];
  const float* tpe_w2 = (const float*)d_in[9];
  const float* tpe_b2 = (const float*)d_in[10];
  const float* ln1_g = (const float*)d_in[11];
  const float* ln1_b = (const float*)d_in[12];
  const float* wq = (const float*)d_in[13];
  const float* wkv = (const float*)d_in[14];
  const float* wo = (const float*)d_in[15];
  const float* bo = (const float*)d_in[16];
  const float* ln2_g = (const float*)d_in[17];
  const float* ln2_b = (const float*)d_in[18];
  const float* ffn_w1 = (const float*)d_in[19];
  const float* ffn_b1 = (const float*)d_in[20];
  const float* ffn_w2 = (const float*)d_in[21];
  const float* ffn_b2 = (const float*)d_in[22];
  const float* tm_w1 = (const float*)d_in[23];
  const float* tm_b1 = (const float*)d_in[24];
  const float* tm_w2 = (const float*)d_in[25];
  const float* tm_b2 = (const float*)d_in[26];
  const float* fn_g = (const float*)d_in[27];
  const float* fn_b = (const float*)d_in[28];
  const float* out_w1 = (const float*)d_in[29];
  const float* out_b1 = (const float*)d_in[30];
  const float* out_w2 = (const float*)d_in[31];
  const float* out_b2 = (const float*)d_in[32];

  // Workspace layout (float offsets). Base region identical to round 8.
  float* w = (float*)d_ws;
  float* te = w + 0;
  float* tpe_mid = w + 1024;
  float* time_emb = w + 5120;
  float* tm_mid = w + 6144;
  float* tm = w + 55296;
  float* hbuf = w + 131072;                 // 2176x512 fp32
  u16* q16 = (u16*)(w + 1245184);           // 2176x512 bf16
  float* buf1 = w + 1245184;                // conv stage alias
  u16* hb16 = (u16*)(w + 1802240);          // 2176x512 bf16
  u16* k16 = (u16*)(w + 2359296);           // 2176x64 bf16
  u16* vT16 = (u16*)(w + 2428928);          // 64x2176 bf16
  u16* mid16 = (u16*)(w + 2498560);         // 2176x2048 bf16 (2228224 fl)
  u16* im16 = mid16;
  u16* g16 = mid16;
  u16* wbuf = (u16*)(w + 4726784);          // per-layer weights (fallback)
  u16* wq16 = wbuf;
  u16* wkv16 = wbuf + 262144;
  u16* wo16 = wbuf + 327680;
  u16* w116 = wbuf + 589824;
  u16* w216 = wbuf + 1638400;
  u16* cw216 = wbuf;                        // stem alias
  u16* ow116 = wbuf;                        // head alias
  float* pmlp = hbuf;                       // M=2 MLP partials
  float* pmid = w + 2498560;                // q/kv/wo split-K partials
  // Extended regions (big-workspace path):
  float* part2 = w + 6070272;               // ffn2 partials (2228224 fl)
  float* pqkv = w + 8298496;                // fused qkv partials (2785280 fl)
  float* amlh = w + 11083776;               // attn S=4 (m,l) (139264 fl)
  u16* wall = (u16*)(w + 11362304);         // 12-layer bf16 weight arena
                                            // (16121856 fl) ends 27484160
  u16* opart16h = (u16*)(w + 2498560);      // attn S=4 partial O (fits mid16)
  int big = ws_size >= (size_t)(6070272 + 2228224) * 4 ? 1 : 0;
  int huge = ws_size >= (size_t)120 * 1024 * 1024 ? 1 : 0;

  // --- time embedding + time-MLP pipeline (split-K, two-phase) ---
  te_k<<<1, 512, 0, stream>>>(timesteps, te);
  mlpA_k<<<dim3(32, 4, 1), 256, 0, stream>>>(te, tpe_w1, pmlp, 512, 2048, 0, 0);
  mlpB_k<<<16, 256, 0, stream>>>(pmlp, tpe_b1, tpe_mid, 2048, 11, 4, 1, 0, 0);
  mlpA_k<<<dim3(8, 16, 1), 256, 0, stream>>>(tpe_mid, tpe_w2, pmlp, 2048, 512,
                                             0, 0);
  mlpB_k<<<4, 256, 0, stream>>>(pmlp, tpe_b2, time_emb, 512, 9, 16, 0, 0, 0);
  mlpA_k<<<dim3(32, 4, 12), 256, 0, stream>>>(time_emb, tm_w1, pmlp, 512, 2048,
                                              0, 512L * 2048);
  mlpB_k<<<192, 256, 0, stream>>>(pmlp, tm_b1, tm_mid, 2048, 11, 4, 1, 2048,
                                  2L * 2048);
  mlpA_k<<<dim3(8, 16, 12), 256, 0, stream>>>(tm_mid, tm_w2, pmlp, 2048, 512,
                                              2L * 2048, 2048L * 512);
  mlpB_k<<<48, 256, 0, stream>>>(pmlp, tm_b2, tm, 512, 9, 16, 0, 512,
                                 2L * 512);

  // --- conv stem ---
  conv1_k<<<2048, 256, 0, stream>>>(x, conv_w1, conv_b1, buf1);
  fcvt_k<<<896, 256, 0, stream>>>(conv_w2, cw216, 917504);
  im2col_k<<<14336, 256, 0, stream>>>(buf1, im16);
  bgemm2_k<<<dim3(8, 32, 1), 256, 0, stream>>>(
      im16, cw216, conv_b2, nullptr, nullptr, hbuf, nullptr, nullptr, nullptr,
      1792, 512, 1792, 0, MODE_BIAS | MODE_RELU | MODE_CONVROW);
  cond_k<<<256, 256, 0, stream>>>(cond, hbuf);

  if (huge) {
    // convert ALL layer weights in one launch
    wcvt5b_k<<<dim3(656, 12), 256, 0, stream>>>(wq, wkv, wo, ffn_w1, ffn_w2,
                                                wall);
    // layer 0 ln1 (later layers fold ln1 into ffn2's bredln)
    ln_k<<<2176, 256, 0, stream>>>(hbuf, hb16, ln1_g, ln1_b);
    for (int l = 0; l < 12; ++l) {
      u16* uW = wall + (size_t)l * 2686976;
      // fused q+kv GEMM: B = [wq(512) ; wkv(128)] rows, N=640, split-K 2
      bgemm2_k<<<dim3(10, 34, 2), 256, 0, stream>>>(
          hb16, uW, nullptr, nullptr, nullptr, nullptr, nullptr, nullptr,
          pqkv, 512, 640, 256, 1392640, 0);
      bred_k<<<1360, 256, 0, stream>>>(pqkv, nullptr, nullptr, nullptr,
                                       nullptr, q16, k16, vT16, 1392640, 640,
                                       2, MODE_QKV);
      // attention KV-split S=4
      attn2_k<<<dim3(17, 8, 8), 256, 0, stream>>>(q16, k16, vT16, opart16h,
                                                  amlh, 4);
      amerge_k<<<1088, 256, 0, stream>>>(opart16h, amlh, q16, 4);
      // wo GEMM split-K 2, then fused reduce+epilogue+ln2
      bgemm2_k<<<dim3(8, 34, 2), 256, 0, stream>>>(
          q16, uW + 327680, nullptr, nullptr, nullptr, nullptr, nullptr,
          nullptr, pmid, 512, 512, 256, 1114112, 0);
      bredln_k<<<2176, 256, 0, stream>>>(pmid, bo + l * 512, tm + l * 1024,
                                         hbuf, hb16, ln2_g + l * 512,
                                         ln2_b + l * 512, 2,
                                         MODE_BIAS | MODE_TM | MODE_RES);
      // ffn1 (no split)
      bgemm2_k<<<dim3(32, 34, 1), 256, 0, stream>>>(
          hb16, uW + 589824, ffn_b1 + l * 2048, nullptr, nullptr, nullptr,
          mid16, nullptr, nullptr, 512, 2048, 512, 0,
          MODE_BIAS | MODE_GELU | MODE_OUT16);
      // ffn2 split-K 2, fused reduce+epilogue+ln1(next) (or final fn)
      bgemm2_k<<<dim3(8, 34, 2), 256, 0, stream>>>(
          mid16, uW + 1638400, nullptr, nullptr, nullptr, nullptr, nullptr,
          nullptr, part2, 2048, 512, 1024, 1114112, 0);
      const float* gp = (l == 11) ? fn_g : ln1_g + (l + 1) * 512;
      const float* bp = (l == 11) ? fn_b : ln1_b + (l + 1) * 512;
      bredln_k<<<2176, 256, 0, stream>>>(part2, ffn_b2 + l * 512, nullptr,
                                         hbuf, hb16, gp, bp, 2,
                                         MODE_BIAS | MODE_RES);
    }
    // head (hb16 already holds fn-normalized activations)
    wcvtT_k<<<128, 256, 0, stream>>>(out_w1, ow116, 512, 1024);
    bgemm2_k<<<dim3(16, 34, 1), 256, 0, stream>>>(
        hb16, ow116, out_b1, nullptr, nullptr, nullptr, g16, nullptr, nullptr,
        512, 1024, 512, 0, MODE_BIAS | MODE_GELU | MODE_OUT16);
    outvec_k<<<2048, 256, 0, stream>>>(g16, out_w2, out_b2, (float*)d_out);
    return;
  }

  // ---------------- fallback: round-8 sequence ----------------
  u16* opart16 = (u16*)(w + 2498560);
  float* aml = w + 2498560 + 1114112;
  for (int l = 0; l < 12; ++l) {
    wcvt5_k<<<656, 256, 0, stream>>>(
        wq + (size_t)l * 512 * 512, wkv + (size_t)l * 512 * 128,
        wo + (size_t)l * 512 * 512, ffn_w1 + (size_t)l * 512 * 2048,
        ffn_w2 + (size_t)l * 2048 * 512, wq16, wkv16, wo16, w116, w216);
    ln_k<<<2176, 256, 0, stream>>>(hbuf, hb16, ln1_g + l * 512,
                                   ln1_b + l * 512);
    bgemm2_k<<<dim3(8, 34, 2), 256, 0, stream>>>(
        hb16, wq16, nullptr, nullptr, nullptr, nullptr, nullptr, nullptr,
        pmid, 512, 512, 256, 1114112, 0);
    bred_k<<<1088, 256, 0, stream>>>(pmid, nullptr, nullptr, nullptr, nullptr,
                                     q16, nullptr, nullptr, 1114112, 512, 2,
                                     MODE_OUT16);
    bgemm2_k<<<dim3(2, 34, 2), 256, 0, stream>>>(
        hb16, wkv16, nullptr, nullptr, nullptr, nullptr, nullptr, nullptr,
        pmid, 512, 128, 256, 278528, 0);
    bred_k<<<272, 256, 0, stream>>>(pmid, nullptr, nullptr, nullptr, nullptr,
                                    k16, vT16, nullptr, 278528, 128, 2,
                                    MODE_KVT);
    attn2_k<<<dim3(17, 8, 4), 256, 0, stream>>>(q16, k16, vT16, opart16, aml,
                                                2);
    amerge_k<<<1088, 256, 0, stream>>>(opart16, aml, q16, 2);
    bgemm2_k<<<dim3(8, 34, 2), 256, 0, stream>>>(
        q16, wo16, nullptr, nullptr, nullptr, nullptr, nullptr, nullptr, pmid,
        512, 512, 256, 1114112, 0);
    bred_k<<<1088, 256, 0, stream>>>(pmid, bo + l * 512, tm + l * 1024, hbuf,
                                     hbuf, nullptr, nullptr, nullptr, 1114112,
                                     512, 2, MODE_BIAS | MODE_TM | MODE_RES);
    ln_k<<<2176, 256, 0, stream>>>(hbuf, hb16, ln2_g + l * 512,
                                   ln2_b + l * 512);
    bgemm2_k<<<dim3(32, 34, 1), 256, 0, stream>>>(
        hb16, w116, ffn_b1 + l * 2048, nullptr, nullptr, nullptr, mid16,
        nullptr, nullptr, 512, 2048, 512, 0,
        MODE_BIAS | MODE_GELU | MODE_OUT16);
    if (big) {
      bgemm2_k<<<dim3(8, 34, 2), 256, 0, stream>>>(
          mid16, w216, nullptr, nullptr, nullptr, nullptr, nullptr, nullptr,
          part2, 2048, 512, 1024, 1114112, 0);
      bred_k<<<1088, 256, 0, stream>>>(part2, ffn_b2 + l * 512, nullptr, hbuf,
                                       hbuf, nullptr, nullptr, nullptr,
                                       1114112, 512, 2, MODE_BIAS | MODE_RES);
    } else {
      bgemm2_k<<<dim3(8, 34, 1), 256, 0, stream>>>(
          mid16, w216, ffn_b2 + l * 512, nullptr, hbuf, hbuf, nullptr,
          nullptr, nullptr, 2048, 512, 2048, 0, MODE_BIAS | MODE_RES);
    }
  }
  ln_k<<<2176, 256, 0, stream>>>(hbuf, hb16, fn_g, fn_b);
  wcvtT_k<<<128, 256, 0, stream>>>(out_w1, ow116, 512, 1024);
  bgemm2_k<<<dim3(16, 34, 1), 256, 0, stream>>>(
      hb16, ow116, out_b1, nullptr, nullptr, nullptr, g16, nullptr, nullptr,
      512, 1024, 512, 0, MODE_BIAS | MODE_GELU | MODE_OUT16);
  outvec_k<<<2048, 256, 0, stream>>>(g16, out_w2, out_b2, (float*)d_out);
}